// Round 1
// baseline (2077.802 us; speedup 1.0000x reference)
//
#include <hip/hip_runtime.h>
#include <math.h>

// ---------------- problem constants ----------------
#define S_LEN 2048
#define NB 4
#define NTOK 8192          // NB * S_LEN
#define DM 128             // d_model
#define DI 256             // d_inner
#define DS 256             // d_state
#define XDBC_N 520         // 8 + 256 + 256

// ---------------- workspace layout (bytes) ----------------
// peak usage = 126,353,408 B (~120.5 MiB)
#define XZ_OFF   0ull                     // 2*8192*512*4 = 33,554,432   (xi-half + z-half; z-half overwritten with silu(z))
#define XI_OFF   33554432ull              // 2*8192*256*4 = 16,777,216
#define XDBC_OFF 50331648ull              // 2*8192*520*4 = 34,078,720
#define DT_OFF   84410368ull              // 16,777,216
#define YG_OFF   101187584ull             // 16,777,216
#define XFB_OFF  117964800ull             // 2*8192*128*4 = 8,388,608
#define H1_OFF   XZ_OFF                   // reuse (xz dead after scan+out-gemm)
#define GLU_OFF  XI_OFF                   // reuse
#define H2_OFF   XDBC_OFF                 // reuse

__device__ __forceinline__ float sigmoidf_(float x) {
    return 1.0f / (1.0f + __expf(-x));
}

// ================= generic fp32 tiled GEMM =================
// C[m,n] = sum_k A[m,k] * W[n,k]  (+ mode-specific gather / epilogue)
// BM=BN=64, BK=32, 256 threads, 4x4 per thread.
// MODE 0: XZ   A = x gathered with per-dir flip          -> xz
// MODE 1: XDBC A = xi                                     -> xdbc (ragged N=520)
// MODE 2: OUT  A = yg; epi: resid x(flip) + c*scale       -> xfb
// MODE 3: H1   A = concat(xf,xb) (k<128 -> A0, else A1)   -> h1 (+bias)
// MODE 4: H2   A = glu                                    -> h2 (+bias)

template <int MODE>
__device__ __forceinline__ const float* arow(const float* A0, const float* A1,
                                             const float* Adir, int m, int k0,
                                             int dir, int lda) {
    if constexpr (MODE == 0) {
        int b = m >> 11, s = m & 2047;
        int s2 = dir ? (S_LEN - 1 - s) : s;
        return A0 + ((long)(b * S_LEN + s2)) * DM + k0;
    } else if constexpr (MODE == 3) {
        if (k0 < DM) return A0 + (long)m * DM + k0;
        return A1 + (long)m * DM + (k0 - DM);
    } else {
        return Adir + (long)m * lda + k0;
    }
}

template <int MODE>
__global__ __launch_bounds__(256) void gemm_k(
    const float* __restrict__ A0, const float* __restrict__ A1,
    const float* __restrict__ W0, const float* __restrict__ W1,
    const float* __restrict__ bias0, const float* __restrict__ bias1,
    const float* __restrict__ resid,
    const float* __restrict__ sc0, const float* __restrict__ sc1,
    float* __restrict__ C, int N, int K, int lda, int ldc,
    long aDirStride, long cDirStride) {
    const int dir = blockIdx.z;
    const int m0 = blockIdx.x * 64;
    const int n0 = blockIdx.y * 64;
    const float* W = dir ? W1 : W0;
    const float* bias = dir ? bias1 : bias0;
    const float* Adir = A0 + (long)dir * aDirStride;
    float* Cp = C + (long)dir * cDirStride;

    __shared__ float As[32][68];
    __shared__ float Ws[32][68];

    const int tid = threadIdx.x;
    const int rr = tid >> 3;   // 0..31
    const int cq = tid & 7;    // 0..7 (col quad)
    const int tm = tid & 15;   // m-thread
    const int tn = tid >> 4;   // n-thread

    float acc[4][4];
#pragma unroll
    for (int i = 0; i < 4; ++i)
#pragma unroll
        for (int j = 0; j < 4; ++j) acc[i][j] = 0.f;

    for (int k0 = 0; k0 < K; k0 += 32) {
        // ---- stage A tile (transposed: As[k][m]) ----
#pragma unroll
        for (int h = 0; h < 2; ++h) {
            int m = m0 + rr + h * 32;
            const float* ap = arow<MODE>(A0, A1, Adir, m, k0, dir, lda);
            float4 v = *(const float4*)(ap + cq * 4);
            As[cq * 4 + 0][rr + h * 32] = v.x;
            As[cq * 4 + 1][rr + h * 32] = v.y;
            As[cq * 4 + 2][rr + h * 32] = v.z;
            As[cq * 4 + 3][rr + h * 32] = v.w;
        }
        // ---- stage W tile (transposed: Ws[k][n]), guard ragged N ----
#pragma unroll
        for (int h = 0; h < 2; ++h) {
            int n = n0 + rr + h * 32;
            float4 v;
            if (n < N)
                v = *(const float4*)(W + (long)n * K + k0 + cq * 4);
            else
                v = make_float4(0.f, 0.f, 0.f, 0.f);
            Ws[cq * 4 + 0][rr + h * 32] = v.x;
            Ws[cq * 4 + 1][rr + h * 32] = v.y;
            Ws[cq * 4 + 2][rr + h * 32] = v.z;
            Ws[cq * 4 + 3][rr + h * 32] = v.w;
        }
        __syncthreads();
#pragma unroll
        for (int kk = 0; kk < 32; ++kk) {
            float4 a = *(const float4*)&As[kk][tm * 4];
            float4 w = *(const float4*)&Ws[kk][tn * 4];
            acc[0][0] = fmaf(a.x, w.x, acc[0][0]);
            acc[0][1] = fmaf(a.x, w.y, acc[0][1]);
            acc[0][2] = fmaf(a.x, w.z, acc[0][2]);
            acc[0][3] = fmaf(a.x, w.w, acc[0][3]);
            acc[1][0] = fmaf(a.y, w.x, acc[1][0]);
            acc[1][1] = fmaf(a.y, w.y, acc[1][1]);
            acc[1][2] = fmaf(a.y, w.z, acc[1][2]);
            acc[1][3] = fmaf(a.y, w.w, acc[1][3]);
            acc[2][0] = fmaf(a.z, w.x, acc[2][0]);
            acc[2][1] = fmaf(a.z, w.y, acc[2][1]);
            acc[2][2] = fmaf(a.z, w.z, acc[2][2]);
            acc[2][3] = fmaf(a.z, w.w, acc[2][3]);
            acc[3][0] = fmaf(a.w, w.x, acc[3][0]);
            acc[3][1] = fmaf(a.w, w.y, acc[3][1]);
            acc[3][2] = fmaf(a.w, w.z, acc[3][2]);
            acc[3][3] = fmaf(a.w, w.w, acc[3][3]);
        }
        __syncthreads();
    }

    // ---- epilogue + store ----
    const int n = n0 + tn * 4;
#pragma unroll
    for (int i = 0; i < 4; ++i) {
        int m = m0 + tm * 4 + i;
        float4 v = make_float4(acc[i][0], acc[i][1], acc[i][2], acc[i][3]);
        if constexpr (MODE == 2) {
            int b = m >> 11, s = m & 2047;
            int s2 = dir ? (S_LEN - 1 - s) : s;
            const float* xr = resid + ((long)(b * S_LEN + s2)) * DM + n;
            const float* sc = dir ? sc1 : sc0;
            v.x = fmaf(v.x, sc[n + 0], xr[0]);
            v.y = fmaf(v.y, sc[n + 1], xr[1]);
            v.z = fmaf(v.z, sc[n + 2], xr[2]);
            v.w = fmaf(v.w, sc[n + 3], xr[3]);
        } else if constexpr (MODE == 3 || MODE == 4) {
            v.x += bias[n + 0];
            v.y += bias[n + 1];
            v.z += bias[n + 2];
            v.w += bias[n + 3];
        }
        if (n < N) *(float4*)(Cp + (long)m * ldc + n) = v;
    }
}

// ================= causal dwconv(K=4)+silu on xi-half; silu(z) in place =================
__global__ __launch_bounds__(256) void conv_silu_k(
    float* __restrict__ xz, const float* __restrict__ cw0,
    const float* __restrict__ cw1, const float* __restrict__ cb0,
    const float* __restrict__ cb1, float* __restrict__ xi) {
    const int dir = blockIdx.y;
    const int tok = blockIdx.x;  // 0..8191
    const int c = threadIdx.x;   // 0..255
    const int s = tok & 2047;
    const long base = ((long)dir * NTOK + tok) * 512;

    const float* cw = dir ? cw1 : cw0;
    float4 w = *(const float4*)(cw + c * 4);
    float a = (dir ? cb1 : cb0)[c];
    float v0 = (s >= 3) ? xz[base - 3 * 512 + c] : 0.f;
    float v1 = (s >= 2) ? xz[base - 2 * 512 + c] : 0.f;
    float v2 = (s >= 1) ? xz[base - 1 * 512 + c] : 0.f;
    float v3 = xz[base + c];
    a = fmaf(w.x, v0, fmaf(w.y, v1, fmaf(w.z, v2, fmaf(w.w, v3, a))));
    xi[((long)dir * NTOK + tok) * 256 + c] = a * sigmoidf_(a);

    float z = xz[base + 256 + c];
    xz[base + 256 + c] = z * sigmoidf_(z);  // pre-gate: silu(z), read only by scan
}

// ================= dt = softplus(dtraw @ Wdt^T + bdt) =================
__global__ __launch_bounds__(256) void dt_k(
    const float* __restrict__ xdbc, const float* __restrict__ Wdt0,
    const float* __restrict__ Wdt1, const float* __restrict__ bdt0,
    const float* __restrict__ bdt1, float* __restrict__ dtb) {
    const int dir = blockIdx.y;
    const int tok = blockIdx.x;
    const int d = threadIdx.x;  // 0..255
    __shared__ float r[8];
    const long row = ((long)dir * NTOK + tok) * XDBC_N;
    if (d < 8) r[d] = xdbc[row + d];
    __syncthreads();
    const float* Wd = (dir ? Wdt1 : Wdt0) + d * 8;
    float a = (dir ? bdt1 : bdt0)[d];
#pragma unroll
    for (int k = 0; k < 8; ++k) a = fmaf(r[k], Wd[k], a);
    float sp = (a > 15.f) ? a : log1pf(__expf(a));
    dtb[((long)dir * NTOK + tok) * 256 + d] = sp;
}

// ================= selective scan (fused u*D + silu(z) gate) =================
// one wave per (dir,b,d); lanes = n (4 states/lane); butterfly-reduce y each t
__global__ __launch_bounds__(256) void scan_k(
    const float* __restrict__ xdbc, const float* __restrict__ dtb,
    const float* __restrict__ xi, const float* __restrict__ gzfull,
    const float* __restrict__ Alog0, const float* __restrict__ Alog1,
    const float* __restrict__ D0, const float* __restrict__ D1,
    float* __restrict__ yg) {
    const int wave = threadIdx.x >> 6;
    const int lane = threadIdx.x & 63;
    const int bd = blockIdx.x >> 6;  // 0..7  (grid.x = 512)
    const int dg = blockIdx.x & 63;  // 0..63
    const int dir = bd >> 2, b = bd & 3;
    const int d = dg * 4 + wave;

    const float* Alog = dir ? Alog1 : Alog0;
    const float Dv = (dir ? D1 : D0)[d];
    const float LOG2E = 1.4426950408889634f;
    float A2[4], h[4] = {0.f, 0.f, 0.f, 0.f};
#pragma unroll
    for (int j = 0; j < 4; ++j)
        A2[j] = -expf(Alog[(long)d * DS + lane + 64 * j]) * LOG2E;

    const long tokBase = (long)dir * NTOK + (long)b * S_LEN;
    const float* xrow = xdbc + tokBase * XDBC_N;
    const float* dtp = dtb + tokBase * 256 + d;
    const float* up = xi + tokBase * 256 + d;
    const float* gzp = gzfull + tokBase * 512 + 256 + d;
    float* yp = yg + tokBase * 256 + d;

#pragma unroll 4
    for (int t = 0; t < S_LEN; ++t) {
        const float* r = xrow + (long)t * XDBC_N;
        float Bv0 = r[8 + lane], Bv1 = r[72 + lane];
        float Bv2 = r[136 + lane], Bv3 = r[200 + lane];
        float Cv0 = r[264 + lane], Cv1 = r[328 + lane];
        float Cv2 = r[392 + lane], Cv3 = r[456 + lane];
        float dtv = dtp[(long)t * 256];
        float uv = up[(long)t * 256];
        float p = dtv * uv;

        float acc;
        h[0] = fmaf(h[0], exp2f(dtv * A2[0]), p * Bv0);
        acc = h[0] * Cv0;
        h[1] = fmaf(h[1], exp2f(dtv * A2[1]), p * Bv1);
        acc = fmaf(h[1], Cv1, acc);
        h[2] = fmaf(h[2], exp2f(dtv * A2[2]), p * Bv2);
        acc = fmaf(h[2], Cv2, acc);
        h[3] = fmaf(h[3], exp2f(dtv * A2[3]), p * Bv3);
        acc = fmaf(h[3], Cv3, acc);

        acc += __shfl_xor(acc, 1);
        acc += __shfl_xor(acc, 2);
        acc += __shfl_xor(acc, 4);
        acc += __shfl_xor(acc, 8);
        acc += __shfl_xor(acc, 16);
        acc += __shfl_xor(acc, 32);

        if (lane == 0) {
            float y = fmaf(uv, Dv, acc) * gzp[(long)t * 512];
            yp[(long)t * 256] = y;
        }
    }
}

// ================= dwconv_same(K=3) + GLU =================
__global__ __launch_bounds__(256) void dwglu_k(
    const float* __restrict__ h1, const float* __restrict__ dww,
    const float* __restrict__ dwb, float* __restrict__ glu) {
    const int tok = blockIdx.x;
    const int c = threadIdx.x;  // 0..255
    const int s = tok & 2047;
    const long row = (long)tok * 512;
    const int c2 = c + 256;

    float xm_a = (s >= 1) ? h1[row - 512 + c] : 0.f;
    float x0_a = h1[row + c];
    float xp_a = (s <= 2046) ? h1[row + 512 + c] : 0.f;
    float xm_b = (s >= 1) ? h1[row - 512 + c2] : 0.f;
    float x0_b = h1[row + c2];
    float xp_b = (s <= 2046) ? h1[row + 512 + c2] : 0.f;

    float a1 = dwb[c];
    a1 = fmaf(dww[c * 3 + 0], xm_a, a1);
    a1 = fmaf(dww[c * 3 + 1], x0_a, a1);
    a1 = fmaf(dww[c * 3 + 2], xp_a, a1);
    float a2 = dwb[c2];
    a2 = fmaf(dww[c2 * 3 + 0], xm_b, a2);
    a2 = fmaf(dww[c2 * 3 + 1], x0_b, a2);
    a2 = fmaf(dww[c2 * 3 + 2], xp_b, a2);

    glu[(long)tok * 256 + c] = a1 * sigmoidf_(a1) * a2;
}

// ================= grouped rms norm (4 groups of 32) =================
__global__ __launch_bounds__(128) void rmsnorm_k(
    const float* __restrict__ h2, const float* __restrict__ gamma,
    float* __restrict__ out) {
    const int tok = blockIdx.x;
    const int c = threadIdx.x;  // 0..127; groups of 32 within each wave-half
    float v = h2[(long)tok * 128 + c];
    float ss = v * v;
    ss += __shfl_xor(ss, 1);
    ss += __shfl_xor(ss, 2);
    ss += __shfl_xor(ss, 4);
    ss += __shfl_xor(ss, 8);
    ss += __shfl_xor(ss, 16);
    float r = sqrtf(ss * (1.0f / 32.0f));
    out[(long)tok * 128 + c] = v / (r + 1e-5f) * gamma[c];
}

// ================= host launcher =================
extern "C" void kernel_launch(void* const* d_in, const int* in_sizes, int n_in,
                              void* d_out, int out_size, void* d_ws,
                              size_t ws_size, hipStream_t stream) {
    const float* x = (const float*)d_in[0];
    const float* f_Win = (const float*)d_in[1];
    const float* f_convw = (const float*)d_in[2];
    const float* f_convb = (const float*)d_in[3];
    const float* f_Wx = (const float*)d_in[4];
    const float* f_Wdt = (const float*)d_in[5];
    const float* f_bdt = (const float*)d_in[6];
    const float* f_Alog = (const float*)d_in[7];
    const float* f_D = (const float*)d_in[8];
    const float* f_Wout = (const float*)d_in[9];
    const float* b_Win = (const float*)d_in[10];
    const float* b_convw = (const float*)d_in[11];
    const float* b_convb = (const float*)d_in[12];
    const float* b_Wx = (const float*)d_in[13];
    const float* b_Wdt = (const float*)d_in[14];
    const float* b_bdt = (const float*)d_in[15];
    const float* b_Alog = (const float*)d_in[16];
    const float* b_D = (const float*)d_in[17];
    const float* b_Wout = (const float*)d_in[18];
    const float* fscale = (const float*)d_in[19];
    const float* bscale = (const float*)d_in[20];
    const float* convf_w = (const float*)d_in[21];
    const float* convf_b = (const float*)d_in[22];
    const float* dw_w = (const float*)d_in[23];
    const float* dw_b = (const float*)d_in[24];
    const float* convo_w = (const float*)d_in[25];
    const float* convo_b = (const float*)d_in[26];
    const float* gamma = (const float*)d_in[27];

    char* ws = (char*)d_ws;
    float* xz = (float*)(ws + XZ_OFF);
    float* xi = (float*)(ws + XI_OFF);
    float* xdbc = (float*)(ws + XDBC_OFF);
    float* dtb = (float*)(ws + DT_OFF);
    float* yg = (float*)(ws + YG_OFF);
    float* xfb = (float*)(ws + XFB_OFF);
    float* h1 = (float*)(ws + H1_OFF);
    float* glu = (float*)(ws + GLU_OFF);
    float* h2 = (float*)(ws + H2_OFF);
    float* out = (float*)d_out;

    // 1) xz = x(flip per dir) @ Win^T      (both dirs)
    gemm_k<0><<<dim3(128, 8, 2), 256, 0, stream>>>(
        x, nullptr, f_Win, b_Win, nullptr, nullptr, nullptr, nullptr, nullptr,
        xz, 512, 128, 128, 512, 0, (long)NTOK * 512);
    // 2) xi = silu(causal_conv4(xz[:, :256])); xz z-half := silu(z)
    conv_silu_k<<<dim3(NTOK, 2), 256, 0, stream>>>(xz, f_convw, b_convw,
                                                   f_convb, b_convb, xi);
    // 3) xdbc = xi @ Wx^T (N=520 ragged)
    gemm_k<1><<<dim3(128, 9, 2), 256, 0, stream>>>(
        xi, nullptr, f_Wx, b_Wx, nullptr, nullptr, nullptr, nullptr, nullptr,
        xdbc, 520, 256, 256, 520, (long)NTOK * 256, (long)NTOK * 520);
    // 4) dt = softplus(dtraw @ Wdt^T + bdt)
    dt_k<<<dim3(NTOK, 2), 256, 0, stream>>>(xdbc, f_Wdt, b_Wdt, f_bdt, b_bdt,
                                            dtb);
    // 5) selective scan -> yg = (scan + u*D) * silu(z)
    scan_k<<<512, 256, 0, stream>>>(xdbc, dtb, xi, xz, f_Alog, b_Alog, f_D,
                                    b_D, yg);
    // 6) xfb[dir] = x(flip) + (yg @ Wout^T) * scale
    gemm_k<2><<<dim3(128, 2, 2), 256, 0, stream>>>(
        yg, nullptr, f_Wout, b_Wout, nullptr, nullptr, x, fscale, bscale, xfb,
        128, 256, 256, 128, (long)NTOK * 256, (long)NTOK * 128);
    // 7) h1 = concat(xf, xb) @ convf_w^T + convf_b
    gemm_k<3><<<dim3(128, 8, 1), 256, 0, stream>>>(
        xfb, xfb + (long)NTOK * 128, convf_w, convf_w, convf_b, convf_b,
        nullptr, nullptr, nullptr, h1, 512, 256, 128, 512, 0, 0);
    // 8) dwconv3(same) + GLU
    dwglu_k<<<NTOK, 256, 0, stream>>>(h1, dw_w, dw_b, glu);
    // 9) h2 = glu @ convo_w^T + convo_b
    gemm_k<4><<<dim3(128, 2, 1), 256, 0, stream>>>(
        glu, nullptr, convo_w, convo_w, convo_b, convo_b, nullptr, nullptr,
        nullptr, h2, 128, 256, 256, 128, 0, 0);
    // 10) grouped RMS norm -> out
    rmsnorm_k<<<NTOK, 128, 0, stream>>>(h2, gamma, out);
}

// Round 2
// 1002.833 us; speedup vs baseline: 2.0719x; 2.0719x over previous
//
#include <hip/hip_runtime.h>
#include <math.h>

// ---------------- problem constants ----------------
#define S_LEN 2048
#define NB 4
#define NTOK 8192          // NB * S_LEN
#define DM 128             // d_model
#define DI 256             // d_inner
#define DS 256             // d_state
#define XDBC_N 520         // 8 + 256 + 256

// ---------------- workspace layout (bytes) ----------------
// peak usage = 126,353,408 B (~120.5 MiB)
#define XZ_OFF   0ull                     // 2*8192*512*4 = 33,554,432   (xi-half + z-half; z-half overwritten with silu(z))
#define XI_OFF   33554432ull              // 2*8192*256*4 = 16,777,216
#define XDBC_OFF 50331648ull              // 2*8192*520*4 = 34,078,720
#define DT_OFF   84410368ull              // 16,777,216
#define YG_OFF   101187584ull             // 16,777,216
#define XFB_OFF  117964800ull             // 2*8192*128*4 = 8,388,608
#define H1_OFF   XZ_OFF                   // reuse (xz dead after scan+out-gemm)
#define GLU_OFF  XI_OFF                   // reuse
#define H2_OFF   XDBC_OFF                 // reuse

__device__ __forceinline__ float sigmoidf_(float x) {
    return 1.0f / (1.0f + __expf(-x));
}

// ================= generic fp32 tiled GEMM =================
// C[m,n] = sum_k A[m,k] * W[n,k]  (+ mode-specific gather / epilogue)
// BM=BN=64, BK=32, 256 threads, 4x4 per thread.
// MODE 0: XZ   A = x gathered with per-dir flip          -> xz
// MODE 1: XDBC A = xi                                     -> xdbc (ragged N=520)
// MODE 2: OUT  A = yg; epi: resid x(flip) + c*scale       -> xfb
// MODE 3: H1   A = concat(xf,xb) (k<128 -> A0, else A1)   -> h1 (+bias)
// MODE 4: H2   A = glu                                    -> h2 (+bias)

template <int MODE>
__device__ __forceinline__ const float* arow(const float* A0, const float* A1,
                                             const float* Adir, int m, int k0,
                                             int dir, int lda) {
    if constexpr (MODE == 0) {
        int b = m >> 11, s = m & 2047;
        int s2 = dir ? (S_LEN - 1 - s) : s;
        return A0 + ((long)(b * S_LEN + s2)) * DM + k0;
    } else if constexpr (MODE == 3) {
        if (k0 < DM) return A0 + (long)m * DM + k0;
        return A1 + (long)m * DM + (k0 - DM);
    } else {
        return Adir + (long)m * lda + k0;
    }
}

template <int MODE>
__global__ __launch_bounds__(256) void gemm_k(
    const float* __restrict__ A0, const float* __restrict__ A1,
    const float* __restrict__ W0, const float* __restrict__ W1,
    const float* __restrict__ bias0, const float* __restrict__ bias1,
    const float* __restrict__ resid,
    const float* __restrict__ sc0, const float* __restrict__ sc1,
    float* __restrict__ C, int N, int K, int lda, int ldc,
    long aDirStride, long cDirStride) {
    const int dir = blockIdx.z;
    const int m0 = blockIdx.x * 64;
    const int n0 = blockIdx.y * 64;
    const float* W = dir ? W1 : W0;
    const float* bias = dir ? bias1 : bias0;
    const float* Adir = A0 + (long)dir * aDirStride;
    float* Cp = C + (long)dir * cDirStride;

    __shared__ float As[32][68];
    __shared__ float Ws[32][68];

    const int tid = threadIdx.x;
    const int rr = tid >> 3;   // 0..31
    const int cq = tid & 7;    // 0..7 (col quad)
    const int tm = tid & 15;   // m-thread
    const int tn = tid >> 4;   // n-thread

    float acc[4][4];
#pragma unroll
    for (int i = 0; i < 4; ++i)
#pragma unroll
        for (int j = 0; j < 4; ++j) acc[i][j] = 0.f;

    for (int k0 = 0; k0 < K; k0 += 32) {
        // ---- stage A tile (transposed: As[k][m]) ----
#pragma unroll
        for (int h = 0; h < 2; ++h) {
            int m = m0 + rr + h * 32;
            const float* ap = arow<MODE>(A0, A1, Adir, m, k0, dir, lda);
            float4 v = *(const float4*)(ap + cq * 4);
            As[cq * 4 + 0][rr + h * 32] = v.x;
            As[cq * 4 + 1][rr + h * 32] = v.y;
            As[cq * 4 + 2][rr + h * 32] = v.z;
            As[cq * 4 + 3][rr + h * 32] = v.w;
        }
        // ---- stage W tile (transposed: Ws[k][n]), guard ragged N ----
#pragma unroll
        for (int h = 0; h < 2; ++h) {
            int n = n0 + rr + h * 32;
            float4 v;
            if (n < N)
                v = *(const float4*)(W + (long)n * K + k0 + cq * 4);
            else
                v = make_float4(0.f, 0.f, 0.f, 0.f);
            Ws[cq * 4 + 0][rr + h * 32] = v.x;
            Ws[cq * 4 + 1][rr + h * 32] = v.y;
            Ws[cq * 4 + 2][rr + h * 32] = v.z;
            Ws[cq * 4 + 3][rr + h * 32] = v.w;
        }
        __syncthreads();
#pragma unroll
        for (int kk = 0; kk < 32; ++kk) {
            float4 a = *(const float4*)&As[kk][tm * 4];
            float4 w = *(const float4*)&Ws[kk][tn * 4];
            acc[0][0] = fmaf(a.x, w.x, acc[0][0]);
            acc[0][1] = fmaf(a.x, w.y, acc[0][1]);
            acc[0][2] = fmaf(a.x, w.z, acc[0][2]);
            acc[0][3] = fmaf(a.x, w.w, acc[0][3]);
            acc[1][0] = fmaf(a.y, w.x, acc[1][0]);
            acc[1][1] = fmaf(a.y, w.y, acc[1][1]);
            acc[1][2] = fmaf(a.y, w.z, acc[1][2]);
            acc[1][3] = fmaf(a.y, w.w, acc[1][3]);
            acc[2][0] = fmaf(a.z, w.x, acc[2][0]);
            acc[2][1] = fmaf(a.z, w.y, acc[2][1]);
            acc[2][2] = fmaf(a.z, w.z, acc[2][2]);
            acc[2][3] = fmaf(a.z, w.w, acc[2][3]);
            acc[3][0] = fmaf(a.w, w.x, acc[3][0]);
            acc[3][1] = fmaf(a.w, w.y, acc[3][1]);
            acc[3][2] = fmaf(a.w, w.z, acc[3][2]);
            acc[3][3] = fmaf(a.w, w.w, acc[3][3]);
        }
        __syncthreads();
    }

    // ---- epilogue + store ----
    const int n = n0 + tn * 4;
#pragma unroll
    for (int i = 0; i < 4; ++i) {
        int m = m0 + tm * 4 + i;
        float4 v = make_float4(acc[i][0], acc[i][1], acc[i][2], acc[i][3]);
        if constexpr (MODE == 2) {
            int b = m >> 11, s = m & 2047;
            int s2 = dir ? (S_LEN - 1 - s) : s;
            const float* xr = resid + ((long)(b * S_LEN + s2)) * DM + n;
            const float* sc = dir ? sc1 : sc0;
            v.x = fmaf(v.x, sc[n + 0], xr[0]);
            v.y = fmaf(v.y, sc[n + 1], xr[1]);
            v.z = fmaf(v.z, sc[n + 2], xr[2]);
            v.w = fmaf(v.w, sc[n + 3], xr[3]);
        } else if constexpr (MODE == 3 || MODE == 4) {
            v.x += bias[n + 0];
            v.y += bias[n + 1];
            v.z += bias[n + 2];
            v.w += bias[n + 3];
        }
        if (n < N) *(float4*)(Cp + (long)m * ldc + n) = v;
    }
}

// ================= causal dwconv(K=4)+silu on xi-half; silu(z) in place =================
__global__ __launch_bounds__(256) void conv_silu_k(
    float* __restrict__ xz, const float* __restrict__ cw0,
    const float* __restrict__ cw1, const float* __restrict__ cb0,
    const float* __restrict__ cb1, float* __restrict__ xi) {
    const int dir = blockIdx.y;
    const int tok = blockIdx.x;  // 0..8191
    const int c = threadIdx.x;   // 0..255
    const int s = tok & 2047;
    const long base = ((long)dir * NTOK + tok) * 512;

    const float* cw = dir ? cw1 : cw0;
    float4 w = *(const float4*)(cw + c * 4);
    float a = (dir ? cb1 : cb0)[c];
    float v0 = (s >= 3) ? xz[base - 3 * 512 + c] : 0.f;
    float v1 = (s >= 2) ? xz[base - 2 * 512 + c] : 0.f;
    float v2 = (s >= 1) ? xz[base - 1 * 512 + c] : 0.f;
    float v3 = xz[base + c];
    a = fmaf(w.x, v0, fmaf(w.y, v1, fmaf(w.z, v2, fmaf(w.w, v3, a))));
    xi[((long)dir * NTOK + tok) * 256 + c] = a * sigmoidf_(a);

    float z = xz[base + 256 + c];
    xz[base + 256 + c] = z * sigmoidf_(z);  // pre-gate: silu(z), read only by scan
}

// ================= dt = softplus(dtraw @ Wdt^T + bdt) =================
__global__ __launch_bounds__(256) void dt_k(
    const float* __restrict__ xdbc, const float* __restrict__ Wdt0,
    const float* __restrict__ Wdt1, const float* __restrict__ bdt0,
    const float* __restrict__ bdt1, float* __restrict__ dtb) {
    const int dir = blockIdx.y;
    const int tok = blockIdx.x;
    const int d = threadIdx.x;  // 0..255
    __shared__ float r[8];
    const long row = ((long)dir * NTOK + tok) * XDBC_N;
    if (d < 8) r[d] = xdbc[row + d];
    __syncthreads();
    const float* Wd = (dir ? Wdt1 : Wdt0) + d * 8;
    float a = (dir ? bdt1 : bdt0)[d];
#pragma unroll
    for (int k = 0; k < 8; ++k) a = fmaf(r[k], Wd[k], a);
    float sp = (a > 15.f) ? a : log1pf(__expf(a));
    dtb[((long)dir * NTOK + tok) * 256 + d] = sp;
}

// ================= selective scan (fused u*D + silu(z) gate) =================
// one wave per (dir,b,d); lane owns n = 4*lane+j (contiguous -> float4 loads);
// explicit 4-deep register prefetch pipeline; butterfly-reduce y each t.
__global__ __launch_bounds__(256) void scan_k(
    const float* __restrict__ xdbc, const float* __restrict__ dtb,
    const float* __restrict__ xi, const float* __restrict__ gzfull,
    const float* __restrict__ Alog0, const float* __restrict__ Alog1,
    const float* __restrict__ D0, const float* __restrict__ D1,
    float* __restrict__ yg) {
    const int wave = threadIdx.x >> 6;
    const int lane = threadIdx.x & 63;
    const int bd = blockIdx.x >> 6;  // 0..7  (grid.x = 512)
    const int dg = blockIdx.x & 63;  // 0..63
    const int dir = bd >> 2, b = bd & 3;
    const int d = dg * 4 + wave;

    const float* Alog = dir ? Alog1 : Alog0;
    const float Dv = (dir ? D1 : D0)[d];
    const float LOG2E = 1.4426950408889634f;
    // lane owns n = 4*lane + j
    float4 A2;
    {
        const float* ap = Alog + (long)d * DS + 4 * lane;
        A2.x = -__expf(ap[0]) * LOG2E;
        A2.y = -__expf(ap[1]) * LOG2E;
        A2.z = -__expf(ap[2]) * LOG2E;
        A2.w = -__expf(ap[3]) * LOG2E;
    }
    float4 h = make_float4(0.f, 0.f, 0.f, 0.f);

    const long tokBase = (long)dir * NTOK + (long)b * S_LEN;
    const float* xrow = xdbc + tokBase * XDBC_N;
    const float* dtp = dtb + tokBase * 256 + d;
    const float* up = xi + tokBase * 256 + d;
    const float* gzp = gzfull + tokBase * 512 + 256 + d;
    float* yp = yg + tokBase * 256 + d;

    // ---- 4-deep prefetch pipeline ----
    float4 Bs[4], Cs[4];
    float dts[4], us[4], gzs[4];
#define LD_SLOT(q, t)                                                       \
    {                                                                       \
        const float* r_ = xrow + (long)(t) * XDBC_N;                        \
        Bs[q] = *(const float4*)(r_ + 8 + 4 * lane);                        \
        Cs[q] = *(const float4*)(r_ + 264 + 4 * lane);                      \
        dts[q] = dtp[(long)(t) * 256];                                      \
        us[q] = up[(long)(t) * 256];                                        \
        gzs[q] = gzp[(long)(t) * 512];                                      \
    }
    LD_SLOT(0, 0)
    LD_SLOT(1, 1)
    LD_SLOT(2, 2)
    LD_SLOT(3, 3)

    for (int t = 0; t < S_LEN; t += 4) {
#pragma unroll
        for (int q = 0; q < 4; ++q) {
            // pull slot into locals, then immediately refill slot for t+q+4
            float4 Bv = Bs[q], Cv = Cs[q];
            float dtv = dts[q], uv = us[q], gzv = gzs[q];
            int tn = t + q + 4;
            if (tn > S_LEN - 1) tn = S_LEN - 1;  // harmless re-read
            LD_SLOT(q, tn)

            float p = dtv * uv;
            h.x = fmaf(h.x, __builtin_amdgcn_exp2f(dtv * A2.x), p * Bv.x);
            h.y = fmaf(h.y, __builtin_amdgcn_exp2f(dtv * A2.y), p * Bv.y);
            h.z = fmaf(h.z, __builtin_amdgcn_exp2f(dtv * A2.z), p * Bv.z);
            h.w = fmaf(h.w, __builtin_amdgcn_exp2f(dtv * A2.w), p * Bv.w);

            float acc = h.x * Cv.x;
            acc = fmaf(h.y, Cv.y, acc);
            acc = fmaf(h.z, Cv.z, acc);
            acc = fmaf(h.w, Cv.w, acc);

            acc += __shfl_xor(acc, 1);
            acc += __shfl_xor(acc, 2);
            acc += __shfl_xor(acc, 4);
            acc += __shfl_xor(acc, 8);
            acc += __shfl_xor(acc, 16);
            acc += __shfl_xor(acc, 32);

            if (lane == 0) {
                yp[(long)(t + q) * 256] = fmaf(uv, Dv, acc) * gzv;
            }
        }
    }
#undef LD_SLOT
}

// ================= dwconv_same(K=3) + GLU =================
__global__ __launch_bounds__(256) void dwglu_k(
    const float* __restrict__ h1, const float* __restrict__ dww,
    const float* __restrict__ dwb, float* __restrict__ glu) {
    const int tok = blockIdx.x;
    const int c = threadIdx.x;  // 0..255
    const int s = tok & 2047;
    const long row = (long)tok * 512;
    const int c2 = c + 256;

    float xm_a = (s >= 1) ? h1[row - 512 + c] : 0.f;
    float x0_a = h1[row + c];
    float xp_a = (s <= 2046) ? h1[row + 512 + c] : 0.f;
    float xm_b = (s >= 1) ? h1[row - 512 + c2] : 0.f;
    float x0_b = h1[row + c2];
    float xp_b = (s <= 2046) ? h1[row + 512 + c2] : 0.f;

    float a1 = dwb[c];
    a1 = fmaf(dww[c * 3 + 0], xm_a, a1);
    a1 = fmaf(dww[c * 3 + 1], x0_a, a1);
    a1 = fmaf(dww[c * 3 + 2], xp_a, a1);
    float a2 = dwb[c2];
    a2 = fmaf(dww[c2 * 3 + 0], xm_b, a2);
    a2 = fmaf(dww[c2 * 3 + 1], x0_b, a2);
    a2 = fmaf(dww[c2 * 3 + 2], xp_b, a2);

    glu[(long)tok * 256 + c] = a1 * sigmoidf_(a1) * a2;
}

// ================= grouped rms norm (4 groups of 32) =================
__global__ __launch_bounds__(128) void rmsnorm_k(
    const float* __restrict__ h2, const float* __restrict__ gamma,
    float* __restrict__ out) {
    const int tok = blockIdx.x;
    const int c = threadIdx.x;  // 0..127; groups of 32 within each wave-half
    float v = h2[(long)tok * 128 + c];
    float ss = v * v;
    ss += __shfl_xor(ss, 1);
    ss += __shfl_xor(ss, 2);
    ss += __shfl_xor(ss, 4);
    ss += __shfl_xor(ss, 8);
    ss += __shfl_xor(ss, 16);
    float r = sqrtf(ss * (1.0f / 32.0f));
    out[(long)tok * 128 + c] = v / (r + 1e-5f) * gamma[c];
}

// ================= host launcher =================
extern "C" void kernel_launch(void* const* d_in, const int* in_sizes, int n_in,
                              void* d_out, int out_size, void* d_ws,
                              size_t ws_size, hipStream_t stream) {
    const float* x = (const float*)d_in[0];
    const float* f_Win = (const float*)d_in[1];
    const float* f_convw = (const float*)d_in[2];
    const float* f_convb = (const float*)d_in[3];
    const float* f_Wx = (const float*)d_in[4];
    const float* f_Wdt = (const float*)d_in[5];
    const float* f_bdt = (const float*)d_in[6];
    const float* f_Alog = (const float*)d_in[7];
    const float* f_D = (const float*)d_in[8];
    const float* f_Wout = (const float*)d_in[9];
    const float* b_Win = (const float*)d_in[10];
    const float* b_convw = (const float*)d_in[11];
    const float* b_convb = (const float*)d_in[12];
    const float* b_Wx = (const float*)d_in[13];
    const float* b_Wdt = (const float*)d_in[14];
    const float* b_bdt = (const float*)d_in[15];
    const float* b_Alog = (const float*)d_in[16];
    const float* b_D = (const float*)d_in[17];
    const float* b_Wout = (const float*)d_in[18];
    const float* fscale = (const float*)d_in[19];
    const float* bscale = (const float*)d_in[20];
    const float* convf_w = (const float*)d_in[21];
    const float* convf_b = (const float*)d_in[22];
    const float* dw_w = (const float*)d_in[23];
    const float* dw_b = (const float*)d_in[24];
    const float* convo_w = (const float*)d_in[25];
    const float* convo_b = (const float*)d_in[26];
    const float* gamma = (const float*)d_in[27];

    char* ws = (char*)d_ws;
    float* xz = (float*)(ws + XZ_OFF);
    float* xi = (float*)(ws + XI_OFF);
    float* xdbc = (float*)(ws + XDBC_OFF);
    float* dtb = (float*)(ws + DT_OFF);
    float* yg = (float*)(ws + YG_OFF);
    float* xfb = (float*)(ws + XFB_OFF);
    float* h1 = (float*)(ws + H1_OFF);
    float* glu = (float*)(ws + GLU_OFF);
    float* h2 = (float*)(ws + H2_OFF);
    float* out = (float*)d_out;

    // 1) xz = x(flip per dir) @ Win^T      (both dirs)
    gemm_k<0><<<dim3(128, 8, 2), 256, 0, stream>>>(
        x, nullptr, f_Win, b_Win, nullptr, nullptr, nullptr, nullptr, nullptr,
        xz, 512, 128, 128, 512, 0, (long)NTOK * 512);
    // 2) xi = silu(causal_conv4(xz[:, :256])); xz z-half := silu(z)
    conv_silu_k<<<dim3(NTOK, 2), 256, 0, stream>>>(xz, f_convw, b_convw,
                                                   f_convb, b_convb, xi);
    // 3) xdbc = xi @ Wx^T (N=520 ragged)
    gemm_k<1><<<dim3(128, 9, 2), 256, 0, stream>>>(
        xi, nullptr, f_Wx, b_Wx, nullptr, nullptr, nullptr, nullptr, nullptr,
        xdbc, 520, 256, 256, 520, (long)NTOK * 256, (long)NTOK * 520);
    // 4) dt = softplus(dtraw @ Wdt^T + bdt)
    dt_k<<<dim3(NTOK, 2), 256, 0, stream>>>(xdbc, f_Wdt, b_Wdt, f_bdt, b_bdt,
                                            dtb);
    // 5) selective scan -> yg = (scan + u*D) * silu(z)
    scan_k<<<512, 256, 0, stream>>>(xdbc, dtb, xi, xz, f_Alog, b_Alog, f_D,
                                    b_D, yg);
    // 6) xfb[dir] = x(flip) + (yg @ Wout^T) * scale
    gemm_k<2><<<dim3(128, 2, 2), 256, 0, stream>>>(
        yg, nullptr, f_Wout, b_Wout, nullptr, nullptr, x, fscale, bscale, xfb,
        128, 256, 256, 128, (long)NTOK * 256, (long)NTOK * 128);
    // 7) h1 = concat(xf, xb) @ convf_w^T + convf_b
    gemm_k<3><<<dim3(128, 8, 1), 256, 0, stream>>>(
        xfb, xfb + (long)NTOK * 128, convf_w, convf_w, convf_b, convf_b,
        nullptr, nullptr, nullptr, h1, 512, 256, 128, 512, 0, 0);
    // 8) dwconv3(same) + GLU
    dwglu_k<<<NTOK, 256, 0, stream>>>(h1, dw_w, dw_b, glu);
    // 9) h2 = glu @ convo_w^T + convo_b
    gemm_k<4><<<dim3(128, 2, 1), 256, 0, stream>>>(
        glu, nullptr, convo_w, convo_w, convo_b, convo_b, nullptr, nullptr,
        nullptr, h2, 128, 256, 256, 128, 0, 0);
    // 10) grouped RMS norm -> out
    rmsnorm_k<<<NTOK, 128, 0, stream>>>(h2, gamma, out);
}

// Round 3
// 801.081 us; speedup vs baseline: 2.5937x; 1.2518x over previous
//
#include <hip/hip_runtime.h>
#include <math.h>

// ---------------- problem constants ----------------
#define S_LEN 2048
#define NB 4
#define NTOK 8192          // NB * S_LEN
#define DM 128             // d_model
#define DI 256             // d_inner
#define DS 256             // d_state
#define XDBC_N 520         // 8 + 256 + 256

// ---------------- workspace layout (bytes) ----------------
#define XZ_OFF   0ull
#define XI_OFF   33554432ull
#define XDBC_OFF 50331648ull
#define DT_OFF   84410368ull
#define YG_OFF   101187584ull
#define XFB_OFF  117964800ull
#define H1_OFF   XZ_OFF
#define GLU_OFF  XI_OFF
#define H2_OFF   XDBC_OFF

__device__ __forceinline__ float sigmoidf_(float x) {
    return 1.0f / (1.0f + __expf(-x));
}

// ================= generic fp32 tiled GEMM =================
template <int MODE>
__device__ __forceinline__ const float* arow(const float* A0, const float* A1,
                                             const float* Adir, int m, int k0,
                                             int dir, int lda) {
    if constexpr (MODE == 0) {
        int b = m >> 11, s = m & 2047;
        int s2 = dir ? (S_LEN - 1 - s) : s;
        return A0 + ((long)(b * S_LEN + s2)) * DM + k0;
    } else if constexpr (MODE == 3) {
        if (k0 < DM) return A0 + (long)m * DM + k0;
        return A1 + (long)m * DM + (k0 - DM);
    } else {
        return Adir + (long)m * lda + k0;
    }
}

template <int MODE>
__global__ __launch_bounds__(256) void gemm_k(
    const float* __restrict__ A0, const float* __restrict__ A1,
    const float* __restrict__ W0, const float* __restrict__ W1,
    const float* __restrict__ bias0, const float* __restrict__ bias1,
    const float* __restrict__ resid,
    const float* __restrict__ sc0, const float* __restrict__ sc1,
    float* __restrict__ C, int N, int K, int lda, int ldc,
    long aDirStride, long cDirStride) {
    const int dir = blockIdx.z;
    const int m0 = blockIdx.x * 64;
    const int n0 = blockIdx.y * 64;
    const float* W = dir ? W1 : W0;
    const float* bias = dir ? bias1 : bias0;
    const float* Adir = A0 + (long)dir * aDirStride;
    float* Cp = C + (long)dir * cDirStride;

    __shared__ float As[32][68];
    __shared__ float Ws[32][68];

    const int tid = threadIdx.x;
    const int rr = tid >> 3;
    const int cq = tid & 7;
    const int tm = tid & 15;
    const int tn = tid >> 4;

    float acc[4][4];
#pragma unroll
    for (int i = 0; i < 4; ++i)
#pragma unroll
        for (int j = 0; j < 4; ++j) acc[i][j] = 0.f;

    for (int k0 = 0; k0 < K; k0 += 32) {
#pragma unroll
        for (int h = 0; h < 2; ++h) {
            int m = m0 + rr + h * 32;
            const float* ap = arow<MODE>(A0, A1, Adir, m, k0, dir, lda);
            float4 v = *(const float4*)(ap + cq * 4);
            As[cq * 4 + 0][rr + h * 32] = v.x;
            As[cq * 4 + 1][rr + h * 32] = v.y;
            As[cq * 4 + 2][rr + h * 32] = v.z;
            As[cq * 4 + 3][rr + h * 32] = v.w;
        }
#pragma unroll
        for (int h = 0; h < 2; ++h) {
            int n = n0 + rr + h * 32;
            float4 v;
            if (n < N)
                v = *(const float4*)(W + (long)n * K + k0 + cq * 4);
            else
                v = make_float4(0.f, 0.f, 0.f, 0.f);
            Ws[cq * 4 + 0][rr + h * 32] = v.x;
            Ws[cq * 4 + 1][rr + h * 32] = v.y;
            Ws[cq * 4 + 2][rr + h * 32] = v.z;
            Ws[cq * 4 + 3][rr + h * 32] = v.w;
        }
        __syncthreads();
#pragma unroll
        for (int kk = 0; kk < 32; ++kk) {
            float4 a = *(const float4*)&As[kk][tm * 4];
            float4 w = *(const float4*)&Ws[kk][tn * 4];
            acc[0][0] = fmaf(a.x, w.x, acc[0][0]);
            acc[0][1] = fmaf(a.x, w.y, acc[0][1]);
            acc[0][2] = fmaf(a.x, w.z, acc[0][2]);
            acc[0][3] = fmaf(a.x, w.w, acc[0][3]);
            acc[1][0] = fmaf(a.y, w.x, acc[1][0]);
            acc[1][1] = fmaf(a.y, w.y, acc[1][1]);
            acc[1][2] = fmaf(a.y, w.z, acc[1][2]);
            acc[1][3] = fmaf(a.y, w.w, acc[1][3]);
            acc[2][0] = fmaf(a.z, w.x, acc[2][0]);
            acc[2][1] = fmaf(a.z, w.y, acc[2][1]);
            acc[2][2] = fmaf(a.z, w.z, acc[2][2]);
            acc[2][3] = fmaf(a.z, w.w, acc[2][3]);
            acc[3][0] = fmaf(a.w, w.x, acc[3][0]);
            acc[3][1] = fmaf(a.w, w.y, acc[3][1]);
            acc[3][2] = fmaf(a.w, w.z, acc[3][2]);
            acc[3][3] = fmaf(a.w, w.w, acc[3][3]);
        }
        __syncthreads();
    }

    const int n = n0 + tn * 4;
#pragma unroll
    for (int i = 0; i < 4; ++i) {
        int m = m0 + tm * 4 + i;
        float4 v = make_float4(acc[i][0], acc[i][1], acc[i][2], acc[i][3]);
        if constexpr (MODE == 2) {
            int b = m >> 11, s = m & 2047;
            int s2 = dir ? (S_LEN - 1 - s) : s;
            const float* xr = resid + ((long)(b * S_LEN + s2)) * DM + n;
            const float* sc = dir ? sc1 : sc0;
            v.x = fmaf(v.x, sc[n + 0], xr[0]);
            v.y = fmaf(v.y, sc[n + 1], xr[1]);
            v.z = fmaf(v.z, sc[n + 2], xr[2]);
            v.w = fmaf(v.w, sc[n + 3], xr[3]);
        } else if constexpr (MODE == 3 || MODE == 4) {
            v.x += bias[n + 0];
            v.y += bias[n + 1];
            v.z += bias[n + 2];
            v.w += bias[n + 3];
        }
        if (n < N) *(float4*)(Cp + (long)m * ldc + n) = v;
    }
}

// ================= causal dwconv(K=4)+silu; silu(z) in place =================
__global__ __launch_bounds__(256) void conv_silu_k(
    float* __restrict__ xz, const float* __restrict__ cw0,
    const float* __restrict__ cw1, const float* __restrict__ cb0,
    const float* __restrict__ cb1, float* __restrict__ xi) {
    const int dir = blockIdx.y;
    const int tok = blockIdx.x;
    const int c = threadIdx.x;
    const int s = tok & 2047;
    const long base = ((long)dir * NTOK + tok) * 512;

    const float* cw = dir ? cw1 : cw0;
    float4 w = *(const float4*)(cw + c * 4);
    float a = (dir ? cb1 : cb0)[c];
    float v0 = (s >= 3) ? xz[base - 3 * 512 + c] : 0.f;
    float v1 = (s >= 2) ? xz[base - 2 * 512 + c] : 0.f;
    float v2 = (s >= 1) ? xz[base - 1 * 512 + c] : 0.f;
    float v3 = xz[base + c];
    a = fmaf(w.x, v0, fmaf(w.y, v1, fmaf(w.z, v2, fmaf(w.w, v3, a))));
    xi[((long)dir * NTOK + tok) * 256 + c] = a * sigmoidf_(a);

    float z = xz[base + 256 + c];
    xz[base + 256 + c] = z * sigmoidf_(z);
}

// ================= dt = softplus(dtraw @ Wdt^T + bdt) =================
__global__ __launch_bounds__(256) void dt_k(
    const float* __restrict__ xdbc, const float* __restrict__ Wdt0,
    const float* __restrict__ Wdt1, const float* __restrict__ bdt0,
    const float* __restrict__ bdt1, float* __restrict__ dtb) {
    const int dir = blockIdx.y;
    const int tok = blockIdx.x;
    const int d = threadIdx.x;
    __shared__ float r[8];
    const long row = ((long)dir * NTOK + tok) * XDBC_N;
    if (d < 8) r[d] = xdbc[row + d];
    __syncthreads();
    const float* Wd = (dir ? Wdt1 : Wdt0) + d * 8;
    float a = (dir ? bdt1 : bdt0)[d];
#pragma unroll
    for (int k = 0; k < 8; ++k) a = fmaf(r[k], Wd[k], a);
    float sp = (a > 15.f) ? a : log1pf(__expf(a));
    dtb[((long)dir * NTOK + tok) * 256 + d] = sp;
}

// ================= selective scan =================
// one wave per (dir,b,d); lane owns n = 4*lane+j; 8-deep register prefetch;
// 8 timesteps' butterflies batched (ILP=8 across the 6 swizzle stages).
__global__ __launch_bounds__(256) void scan_k(
    const float* __restrict__ xdbc, const float* __restrict__ dtb,
    const float* __restrict__ xi, const float* __restrict__ gzfull,
    const float* __restrict__ Alog0, const float* __restrict__ Alog1,
    const float* __restrict__ D0, const float* __restrict__ D1,
    float* __restrict__ yg) {
    const int wave = threadIdx.x >> 6;
    const int lane = threadIdx.x & 63;
    const int bd = blockIdx.x >> 6;
    const int dg = blockIdx.x & 63;
    const int dir = bd >> 2, b = bd & 3;
    const int d = dg * 4 + wave;

    const float* Alog = dir ? Alog1 : Alog0;
    const float Dv = (dir ? D1 : D0)[d];
    const float LOG2E = 1.4426950408889634f;
    float4 A2;
    {
        const float* ap = Alog + (long)d * DS + 4 * lane;
        A2.x = -__expf(ap[0]) * LOG2E;
        A2.y = -__expf(ap[1]) * LOG2E;
        A2.z = -__expf(ap[2]) * LOG2E;
        A2.w = -__expf(ap[3]) * LOG2E;
    }
    float4 h = make_float4(0.f, 0.f, 0.f, 0.f);

    const long tokBase = (long)dir * NTOK + (long)b * S_LEN;
    const float* xrow = xdbc + tokBase * XDBC_N;
    const float* dtp = dtb + tokBase * 256 + d;
    const float* up = xi + tokBase * 256 + d;
    const float* gzp = gzfull + tokBase * 512 + 256 + d;
    float* yp = yg + tokBase * 256 + d;

    // ---- 8-deep prefetch pipeline ----
    float4 Bs[8], Cs[8];
    float dts[8], us[8], gzs[8];
#define LD_SLOT(q, t)                                                       \
    {                                                                       \
        const float* r_ = xrow + (long)(t) * XDBC_N;                        \
        Bs[q] = *(const float4*)(r_ + 8 + 4 * lane);                        \
        Cs[q] = *(const float4*)(r_ + 264 + 4 * lane);                      \
        dts[q] = dtp[(long)(t) * 256];                                      \
        us[q] = up[(long)(t) * 256];                                        \
        gzs[q] = gzp[(long)(t) * 512];                                      \
    }
#pragma unroll
    for (int q = 0; q < 8; ++q) LD_SLOT(q, q)

    for (int t = 0; t < S_LEN; t += 8) {
        float acc[8], pd[8], gz2[8];
#pragma unroll
        for (int q = 0; q < 8; ++q) {
            float4 Bv = Bs[q], Cv = Cs[q];
            float dtv = dts[q], uv = us[q], gzv = gzs[q];
            int tn = t + q + 8;
            if (tn > S_LEN - 1) tn = S_LEN - 1;  // harmless re-read
            LD_SLOT(q, tn)

            float p = dtv * uv;
            h.x = fmaf(h.x, __builtin_amdgcn_exp2f(dtv * A2.x), p * Bv.x);
            h.y = fmaf(h.y, __builtin_amdgcn_exp2f(dtv * A2.y), p * Bv.y);
            h.z = fmaf(h.z, __builtin_amdgcn_exp2f(dtv * A2.z), p * Bv.z);
            h.w = fmaf(h.w, __builtin_amdgcn_exp2f(dtv * A2.w), p * Bv.w);

            float a0 = h.x * Cv.x;
            a0 = fmaf(h.y, Cv.y, a0);
            a0 = fmaf(h.z, Cv.z, a0);
            acc[q] = fmaf(h.w, Cv.w, a0);
            pd[q] = uv * Dv;
            gz2[q] = gzv;
        }
        // ---- 8 independent 6-stage butterflies (latency overlaps) ----
#pragma unroll
        for (int st = 1; st <= 32; st <<= 1) {
#pragma unroll
            for (int q = 0; q < 8; ++q) acc[q] += __shfl_xor(acc[q], st);
        }
        if (lane == 0) {
#pragma unroll
            for (int q = 0; q < 8; ++q)
                yp[(long)(t + q) * 256] = (pd[q] + acc[q]) * gz2[q];
        }
    }
#undef LD_SLOT
}

// ================= dwconv_same(K=3) + GLU =================
__global__ __launch_bounds__(256) void dwglu_k(
    const float* __restrict__ h1, const float* __restrict__ dww,
    const float* __restrict__ dwb, float* __restrict__ glu) {
    const int tok = blockIdx.x;
    const int c = threadIdx.x;
    const int s = tok & 2047;
    const long row = (long)tok * 512;
    const int c2 = c + 256;

    float xm_a = (s >= 1) ? h1[row - 512 + c] : 0.f;
    float x0_a = h1[row + c];
    float xp_a = (s <= 2046) ? h1[row + 512 + c] : 0.f;
    float xm_b = (s >= 1) ? h1[row - 512 + c2] : 0.f;
    float x0_b = h1[row + c2];
    float xp_b = (s <= 2046) ? h1[row + 512 + c2] : 0.f;

    float a1 = dwb[c];
    a1 = fmaf(dww[c * 3 + 0], xm_a, a1);
    a1 = fmaf(dww[c * 3 + 1], x0_a, a1);
    a1 = fmaf(dww[c * 3 + 2], xp_a, a1);
    float a2 = dwb[c2];
    a2 = fmaf(dww[c2 * 3 + 0], xm_b, a2);
    a2 = fmaf(dww[c2 * 3 + 1], x0_b, a2);
    a2 = fmaf(dww[c2 * 3 + 2], xp_b, a2);

    glu[(long)tok * 256 + c] = a1 * sigmoidf_(a1) * a2;
}

// ================= grouped rms norm (4 groups of 32) =================
__global__ __launch_bounds__(128) void rmsnorm_k(
    const float* __restrict__ h2, const float* __restrict__ gamma,
    float* __restrict__ out) {
    const int tok = blockIdx.x;
    const int c = threadIdx.x;
    float v = h2[(long)tok * 128 + c];
    float ss = v * v;
    ss += __shfl_xor(ss, 1);
    ss += __shfl_xor(ss, 2);
    ss += __shfl_xor(ss, 4);
    ss += __shfl_xor(ss, 8);
    ss += __shfl_xor(ss, 16);
    float r = sqrtf(ss * (1.0f / 32.0f));
    out[(long)tok * 128 + c] = v / (r + 1e-5f) * gamma[c];
}

// ================= host launcher =================
extern "C" void kernel_launch(void* const* d_in, const int* in_sizes, int n_in,
                              void* d_out, int out_size, void* d_ws,
                              size_t ws_size, hipStream_t stream) {
    const float* x = (const float*)d_in[0];
    const float* f_Win = (const float*)d_in[1];
    const float* f_convw = (const float*)d_in[2];
    const float* f_convb = (const float*)d_in[3];
    const float* f_Wx = (const float*)d_in[4];
    const float* f_Wdt = (const float*)d_in[5];
    const float* f_bdt = (const float*)d_in[6];
    const float* f_Alog = (const float*)d_in[7];
    const float* f_D = (const float*)d_in[8];
    const float* f_Wout = (const float*)d_in[9];
    const float* b_Win = (const float*)d_in[10];
    const float* b_convw = (const float*)d_in[11];
    const float* b_convb = (const float*)d_in[12];
    const float* b_Wx = (const float*)d_in[13];
    const float* b_Wdt = (const float*)d_in[14];
    const float* b_bdt = (const float*)d_in[15];
    const float* b_Alog = (const float*)d_in[16];
    const float* b_D = (const float*)d_in[17];
    const float* b_Wout = (const float*)d_in[18];
    const float* fscale = (const float*)d_in[19];
    const float* bscale = (const float*)d_in[20];
    const float* convf_w = (const float*)d_in[21];
    const float* convf_b = (const float*)d_in[22];
    const float* dw_w = (const float*)d_in[23];
    const float* dw_b = (const float*)d_in[24];
    const float* convo_w = (const float*)d_in[25];
    const float* convo_b = (const float*)d_in[26];
    const float* gamma = (const float*)d_in[27];

    char* ws = (char*)d_ws;
    float* xz = (float*)(ws + XZ_OFF);
    float* xi = (float*)(ws + XI_OFF);
    float* xdbc = (float*)(ws + XDBC_OFF);
    float* dtb = (float*)(ws + DT_OFF);
    float* yg = (float*)(ws + YG_OFF);
    float* xfb = (float*)(ws + XFB_OFF);
    float* h1 = (float*)(ws + H1_OFF);
    float* glu = (float*)(ws + GLU_OFF);
    float* h2 = (float*)(ws + H2_OFF);
    float* out = (float*)d_out;

    gemm_k<0><<<dim3(128, 8, 2), 256, 0, stream>>>(
        x, nullptr, f_Win, b_Win, nullptr, nullptr, nullptr, nullptr, nullptr,
        xz, 512, 128, 128, 512, 0, (long)NTOK * 512);
    conv_silu_k<<<dim3(NTOK, 2), 256, 0, stream>>>(xz, f_convw, b_convw,
                                                   f_convb, b_convb, xi);
    gemm_k<1><<<dim3(128, 9, 2), 256, 0, stream>>>(
        xi, nullptr, f_Wx, b_Wx, nullptr, nullptr, nullptr, nullptr, nullptr,
        xdbc, 520, 256, 256, 520, (long)NTOK * 256, (long)NTOK * 520);
    dt_k<<<dim3(NTOK, 2), 256, 0, stream>>>(xdbc, f_Wdt, b_Wdt, f_bdt, b_bdt,
                                            dtb);
    scan_k<<<512, 256, 0, stream>>>(xdbc, dtb, xi, xz, f_Alog, b_Alog, f_D,
                                    b_D, yg);
    gemm_k<2><<<dim3(128, 2, 2), 256, 0, stream>>>(
        yg, nullptr, f_Wout, b_Wout, nullptr, nullptr, x, fscale, bscale, xfb,
        128, 256, 256, 128, (long)NTOK * 256, (long)NTOK * 128);
    gemm_k<3><<<dim3(128, 8, 1), 256, 0, stream>>>(
        xfb, xfb + (long)NTOK * 128, convf_w, convf_w, convf_b, convf_b,
        nullptr, nullptr, nullptr, h1, 512, 256, 128, 512, 0, 0);
    dwglu_k<<<NTOK, 256, 0, stream>>>(h1, dw_w, dw_b, glu);
    gemm_k<4><<<dim3(128, 2, 1), 256, 0, stream>>>(
        glu, nullptr, convo_w, convo_w, convo_b, convo_b, nullptr, nullptr,
        nullptr, h2, 128, 256, 256, 128, 0, 0);
    rmsnorm_k<<<NTOK, 128, 0, stream>>>(h2, gamma, out);
}

// Round 4
// 792.459 us; speedup vs baseline: 2.6220x; 1.0109x over previous
//
#include <hip/hip_runtime.h>
#include <math.h>

// ---------------- problem constants ----------------
#define S_LEN 2048
#define NB 4
#define NTOK 8192          // NB * S_LEN
#define DM 128             // d_model
#define DI 256             // d_inner
#define DS 256             // d_state
#define XDBC_N 520         // 8 + 256 + 256

// ---------------- workspace layout (bytes), peak 117,964,800 ----------------
// live chain: meta | xdbc | xz | xi ; later stages reuse dead regions
#define META_OFF 0ull                      // 2*8192*256*8  = 33,554,432 (dead after scan)
#define XDBC_OFF 33554432ull               // 2*8192*520*4  = 34,078,720 (dead after scan)
#define XZ_OFF   67633152ull               // 2*8192*512*4  = 33,554,432 (dead after dt_k)
#define XI_OFF   101187584ull              // 2*8192*256*4  = 16,777,216 (dead after dt_k)
#define YG_OFF   XI_OFF                    // scan output (xi dead)
#define XFB_OFF  XZ_OFF                    // gemm2 output (xz dead)
#define H1_OFF   META_OFF                  // gemm3 output (meta dead)
#define GLU_OFF  (META_OFF + 16777216ull)
#define H2_OFF   (META_OFF + 25165824ull)

struct alignas(8) Meta {
    _Float16 dt, p, pd, gz;  // dt, dt*u, u*D, silu(z)
};

__device__ __forceinline__ float sigmoidf_(float x) {
    return 1.0f / (1.0f + __expf(-x));
}

// ================= generic fp32 tiled GEMM =================
template <int MODE>
__device__ __forceinline__ const float* arow(const float* A0, const float* A1,
                                             const float* Adir, int m, int k0,
                                             int dir, int lda) {
    if constexpr (MODE == 0) {
        int b = m >> 11, s = m & 2047;
        int s2 = dir ? (S_LEN - 1 - s) : s;
        return A0 + ((long)(b * S_LEN + s2)) * DM + k0;
    } else if constexpr (MODE == 3) {
        if (k0 < DM) return A0 + (long)m * DM + k0;
        return A1 + (long)m * DM + (k0 - DM);
    } else {
        return Adir + (long)m * lda + k0;
    }
}

template <int MODE>
__global__ __launch_bounds__(256) void gemm_k(
    const float* __restrict__ A0, const float* __restrict__ A1,
    const float* __restrict__ W0, const float* __restrict__ W1,
    const float* __restrict__ bias0, const float* __restrict__ bias1,
    const float* __restrict__ resid,
    const float* __restrict__ sc0, const float* __restrict__ sc1,
    float* __restrict__ C, int N, int K, int lda, int ldc,
    long aDirStride, long cDirStride) {
    const int dir = blockIdx.z;
    const int m0 = blockIdx.x * 64;
    const int n0 = blockIdx.y * 64;
    const float* W = dir ? W1 : W0;
    const float* bias = dir ? bias1 : bias0;
    const float* Adir = A0 + (long)dir * aDirStride;
    float* Cp = C + (long)dir * cDirStride;

    __shared__ float As[32][68];
    __shared__ float Ws[32][68];

    const int tid = threadIdx.x;
    const int rr = tid >> 3;
    const int cq = tid & 7;
    const int tm = tid & 15;
    const int tn = tid >> 4;

    float acc[4][4];
#pragma unroll
    for (int i = 0; i < 4; ++i)
#pragma unroll
        for (int j = 0; j < 4; ++j) acc[i][j] = 0.f;

    for (int k0 = 0; k0 < K; k0 += 32) {
#pragma unroll
        for (int h = 0; h < 2; ++h) {
            int m = m0 + rr + h * 32;
            const float* ap = arow<MODE>(A0, A1, Adir, m, k0, dir, lda);
            float4 v = *(const float4*)(ap + cq * 4);
            As[cq * 4 + 0][rr + h * 32] = v.x;
            As[cq * 4 + 1][rr + h * 32] = v.y;
            As[cq * 4 + 2][rr + h * 32] = v.z;
            As[cq * 4 + 3][rr + h * 32] = v.w;
        }
#pragma unroll
        for (int h = 0; h < 2; ++h) {
            int n = n0 + rr + h * 32;
            float4 v;
            if (n < N)
                v = *(const float4*)(W + (long)n * K + k0 + cq * 4);
            else
                v = make_float4(0.f, 0.f, 0.f, 0.f);
            Ws[cq * 4 + 0][rr + h * 32] = v.x;
            Ws[cq * 4 + 1][rr + h * 32] = v.y;
            Ws[cq * 4 + 2][rr + h * 32] = v.z;
            Ws[cq * 4 + 3][rr + h * 32] = v.w;
        }
        __syncthreads();
#pragma unroll
        for (int kk = 0; kk < 32; ++kk) {
            float4 a = *(const float4*)&As[kk][tm * 4];
            float4 w = *(const float4*)&Ws[kk][tn * 4];
            acc[0][0] = fmaf(a.x, w.x, acc[0][0]);
            acc[0][1] = fmaf(a.x, w.y, acc[0][1]);
            acc[0][2] = fmaf(a.x, w.z, acc[0][2]);
            acc[0][3] = fmaf(a.x, w.w, acc[0][3]);
            acc[1][0] = fmaf(a.y, w.x, acc[1][0]);
            acc[1][1] = fmaf(a.y, w.y, acc[1][1]);
            acc[1][2] = fmaf(a.y, w.z, acc[1][2]);
            acc[1][3] = fmaf(a.y, w.w, acc[1][3]);
            acc[2][0] = fmaf(a.z, w.x, acc[2][0]);
            acc[2][1] = fmaf(a.z, w.y, acc[2][1]);
            acc[2][2] = fmaf(a.z, w.z, acc[2][2]);
            acc[2][3] = fmaf(a.z, w.w, acc[2][3]);
            acc[3][0] = fmaf(a.w, w.x, acc[3][0]);
            acc[3][1] = fmaf(a.w, w.y, acc[3][1]);
            acc[3][2] = fmaf(a.w, w.z, acc[3][2]);
            acc[3][3] = fmaf(a.w, w.w, acc[3][3]);
        }
        __syncthreads();
    }

    const int n = n0 + tn * 4;
#pragma unroll
    for (int i = 0; i < 4; ++i) {
        int m = m0 + tm * 4 + i;
        float4 v = make_float4(acc[i][0], acc[i][1], acc[i][2], acc[i][3]);
        if constexpr (MODE == 2) {
            int b = m >> 11, s = m & 2047;
            int s2 = dir ? (S_LEN - 1 - s) : s;
            const float* xr = resid + ((long)(b * S_LEN + s2)) * DM + n;
            const float* sc = dir ? sc1 : sc0;
            v.x = fmaf(v.x, sc[n + 0], xr[0]);
            v.y = fmaf(v.y, sc[n + 1], xr[1]);
            v.z = fmaf(v.z, sc[n + 2], xr[2]);
            v.w = fmaf(v.w, sc[n + 3], xr[3]);
        } else if constexpr (MODE == 3 || MODE == 4) {
            v.x += bias[n + 0];
            v.y += bias[n + 1];
            v.z += bias[n + 2];
            v.w += bias[n + 3];
        }
        if (n < N) *(float4*)(Cp + (long)m * ldc + n) = v;
    }
}

// ================= causal dwconv(K=4)+silu on xi-half =================
__global__ __launch_bounds__(256) void conv_silu_k(
    const float* __restrict__ xz, const float* __restrict__ cw0,
    const float* __restrict__ cw1, const float* __restrict__ cb0,
    const float* __restrict__ cb1, float* __restrict__ xi) {
    const int dir = blockIdx.y;
    const int tok = blockIdx.x;
    const int c = threadIdx.x;
    const int s = tok & 2047;
    const long base = ((long)dir * NTOK + tok) * 512;

    const float* cw = dir ? cw1 : cw0;
    float4 w = *(const float4*)(cw + c * 4);
    float a = (dir ? cb1 : cb0)[c];
    float v0 = (s >= 3) ? xz[base - 3 * 512 + c] : 0.f;
    float v1 = (s >= 2) ? xz[base - 2 * 512 + c] : 0.f;
    float v2 = (s >= 1) ? xz[base - 1 * 512 + c] : 0.f;
    float v3 = xz[base + c];
    a = fmaf(w.x, v0, fmaf(w.y, v1, fmaf(w.z, v2, fmaf(w.w, v3, a))));
    xi[((long)dir * NTOK + tok) * 256 + c] = a * sigmoidf_(a);
}

// ================= dt_k: softplus matvec + pack Meta(dt, dt*u, u*D, silu(z)) =================
// output layout: meta[((dir*4+b)*256+d)*2048 + s]  (wave-contiguous t-stream for scan)
__global__ __launch_bounds__(256) void dt_k(
    const float* __restrict__ xdbc, const float* __restrict__ xi,
    const float* __restrict__ xz, const float* __restrict__ Wdt0,
    const float* __restrict__ Wdt1, const float* __restrict__ bdt0,
    const float* __restrict__ bdt1, const float* __restrict__ D0,
    const float* __restrict__ D1, Meta* __restrict__ meta) {
    const int dir = blockIdx.y;
    const int tok = blockIdx.x;
    const int d = threadIdx.x;
    __shared__ float r[8];
    const long row = ((long)dir * NTOK + tok) * XDBC_N;
    if (d < 8) r[d] = xdbc[row + d];
    __syncthreads();
    const float* Wd = (dir ? Wdt1 : Wdt0) + d * 8;
    float a = (dir ? bdt1 : bdt0)[d];
#pragma unroll
    for (int k = 0; k < 8; ++k) a = fmaf(r[k], Wd[k], a);
    float dt = (a > 15.f) ? a : log1pf(__expf(a));

    float u = xi[((long)dir * NTOK + tok) * 256 + d];
    float z = xz[((long)dir * NTOK + tok) * 512 + 256 + d];
    float gz = z * sigmoidf_(z);
    float Dv = (dir ? D1 : D0)[d];

    const int b = tok >> 11, s = tok & 2047;
    Meta m;
    m.dt = (_Float16)dt;
    m.p = (_Float16)(dt * u);
    m.pd = (_Float16)(u * Dv);
    m.gz = (_Float16)gz;
    meta[(((long)dir * 4 + b) * 256 + d) * 2048 + s] = m;
}

// ================= selective scan =================
// one wave per (dir,b,d); lane owns n = 4*lane+j; 8-deep register prefetch
// (no clamp: overrun reads land in the next ws region, values never used);
// per-(t,d) scalars from packed Meta stream; 8 batched butterflies (ILP=8).
__global__ __launch_bounds__(256) void scan_k(
    const float* __restrict__ xdbc, const Meta* __restrict__ meta,
    const float* __restrict__ Alog0, const float* __restrict__ Alog1,
    float* __restrict__ yg) {
    const int wave = threadIdx.x >> 6;
    const int lane = threadIdx.x & 63;
    const int bd = blockIdx.x >> 6;
    const int dg = blockIdx.x & 63;
    const int dir = bd >> 2, b = bd & 3;
    const int d = dg * 4 + wave;

    const float* Alog = dir ? Alog1 : Alog0;
    const float LOG2E = 1.4426950408889634f;
    float4 A2;
    {
        const float* ap = Alog + (long)d * DS + 4 * lane;
        A2.x = -__expf(ap[0]) * LOG2E;
        A2.y = -__expf(ap[1]) * LOG2E;
        A2.z = -__expf(ap[2]) * LOG2E;
        A2.w = -__expf(ap[3]) * LOG2E;
    }
    float4 h = make_float4(0.f, 0.f, 0.f, 0.f);

    const long tokBase = (long)dir * NTOK + (long)b * S_LEN;
    const float* xrow = xdbc + tokBase * XDBC_N;
    const Meta* mp = meta + (((long)dir * 4 + b) * 256 + d) * 2048;
    float* yp = yg + tokBase * 256 + d;

    // ---- 8-deep prefetch pipeline (linear addressing, no clamps) ----
    float4 Bs[8], Cs[8];
    Meta Ms[8];
#define LD_SLOT(q, t)                                                       \
    {                                                                       \
        const float* r_ = xrow + (long)(t) * XDBC_N;                        \
        Bs[q] = *(const float4*)(r_ + 8 + 4 * lane);                        \
        Cs[q] = *(const float4*)(r_ + 264 + 4 * lane);                      \
        Ms[q] = mp[t];                                                      \
    }
#pragma unroll
    for (int q = 0; q < 8; ++q) LD_SLOT(q, q)

    for (int t = 0; t < S_LEN; t += 8) {
        float acc[8], pd[8], gz2[8];
#pragma unroll
        for (int q = 0; q < 8; ++q) {
            float4 Bv = Bs[q], Cv = Cs[q];
            float dtv = (float)Ms[q].dt;
            float pv = (float)Ms[q].p;
            pd[q] = (float)Ms[q].pd;
            gz2[q] = (float)Ms[q].gz;
            LD_SLOT(q, t + q + 8)  // overrun past S_LEN is harmless (in-ws, unused)

            h.x = fmaf(h.x, __builtin_amdgcn_exp2f(dtv * A2.x), pv * Bv.x);
            h.y = fmaf(h.y, __builtin_amdgcn_exp2f(dtv * A2.y), pv * Bv.y);
            h.z = fmaf(h.z, __builtin_amdgcn_exp2f(dtv * A2.z), pv * Bv.z);
            h.w = fmaf(h.w, __builtin_amdgcn_exp2f(dtv * A2.w), pv * Bv.w);

            float a0 = h.x * Cv.x;
            a0 = fmaf(h.y, Cv.y, a0);
            a0 = fmaf(h.z, Cv.z, a0);
            acc[q] = fmaf(h.w, Cv.w, a0);
        }
        // ---- 8 independent 6-stage butterflies ----
#pragma unroll
        for (int st = 1; st <= 32; st <<= 1) {
#pragma unroll
            for (int q = 0; q < 8; ++q) acc[q] += __shfl_xor(acc[q], st);
        }
        if (lane == 0) {
#pragma unroll
            for (int q = 0; q < 8; ++q)
                yp[(long)(t + q) * 256] = (pd[q] + acc[q]) * gz2[q];
        }
    }
#undef LD_SLOT
}

// ================= dwconv_same(K=3) + GLU =================
__global__ __launch_bounds__(256) void dwglu_k(
    const float* __restrict__ h1, const float* __restrict__ dww,
    const float* __restrict__ dwb, float* __restrict__ glu) {
    const int tok = blockIdx.x;
    const int c = threadIdx.x;
    const int s = tok & 2047;
    const long row = (long)tok * 512;
    const int c2 = c + 256;

    float xm_a = (s >= 1) ? h1[row - 512 + c] : 0.f;
    float x0_a = h1[row + c];
    float xp_a = (s <= 2046) ? h1[row + 512 + c] : 0.f;
    float xm_b = (s >= 1) ? h1[row - 512 + c2] : 0.f;
    float x0_b = h1[row + c2];
    float xp_b = (s <= 2046) ? h1[row + 512 + c2] : 0.f;

    float a1 = dwb[c];
    a1 = fmaf(dww[c * 3 + 0], xm_a, a1);
    a1 = fmaf(dww[c * 3 + 1], x0_a, a1);
    a1 = fmaf(dww[c * 3 + 2], xp_a, a1);
    float a2 = dwb[c2];
    a2 = fmaf(dww[c2 * 3 + 0], xm_b, a2);
    a2 = fmaf(dww[c2 * 3 + 1], x0_b, a2);
    a2 = fmaf(dww[c2 * 3 + 2], xp_b, a2);

    glu[(long)tok * 256 + c] = a1 * sigmoidf_(a1) * a2;
}

// ================= grouped rms norm (4 groups of 32) =================
__global__ __launch_bounds__(128) void rmsnorm_k(
    const float* __restrict__ h2, const float* __restrict__ gamma,
    float* __restrict__ out) {
    const int tok = blockIdx.x;
    const int c = threadIdx.x;
    float v = h2[(long)tok * 128 + c];
    float ss = v * v;
    ss += __shfl_xor(ss, 1);
    ss += __shfl_xor(ss, 2);
    ss += __shfl_xor(ss, 4);
    ss += __shfl_xor(ss, 8);
    ss += __shfl_xor(ss, 16);
    float r = sqrtf(ss * (1.0f / 32.0f));
    out[(long)tok * 128 + c] = v / (r + 1e-5f) * gamma[c];
}

// ================= host launcher =================
extern "C" void kernel_launch(void* const* d_in, const int* in_sizes, int n_in,
                              void* d_out, int out_size, void* d_ws,
                              size_t ws_size, hipStream_t stream) {
    const float* x = (const float*)d_in[0];
    const float* f_Win = (const float*)d_in[1];
    const float* f_convw = (const float*)d_in[2];
    const float* f_convb = (const float*)d_in[3];
    const float* f_Wx = (const float*)d_in[4];
    const float* f_Wdt = (const float*)d_in[5];
    const float* f_bdt = (const float*)d_in[6];
    const float* f_Alog = (const float*)d_in[7];
    const float* f_D = (const float*)d_in[8];
    const float* f_Wout = (const float*)d_in[9];
    const float* b_Win = (const float*)d_in[10];
    const float* b_convw = (const float*)d_in[11];
    const float* b_convb = (const float*)d_in[12];
    const float* b_Wx = (const float*)d_in[13];
    const float* b_Wdt = (const float*)d_in[14];
    const float* b_bdt = (const float*)d_in[15];
    const float* b_Alog = (const float*)d_in[16];
    const float* b_D = (const float*)d_in[17];
    const float* b_Wout = (const float*)d_in[18];
    const float* fscale = (const float*)d_in[19];
    const float* bscale = (const float*)d_in[20];
    const float* convf_w = (const float*)d_in[21];
    const float* convf_b = (const float*)d_in[22];
    const float* dw_w = (const float*)d_in[23];
    const float* dw_b = (const float*)d_in[24];
    const float* convo_w = (const float*)d_in[25];
    const float* convo_b = (const float*)d_in[26];
    const float* gamma = (const float*)d_in[27];

    char* ws = (char*)d_ws;
    Meta* meta = (Meta*)(ws + META_OFF);
    float* xdbc = (float*)(ws + XDBC_OFF);
    float* xz = (float*)(ws + XZ_OFF);
    float* xi = (float*)(ws + XI_OFF);
    float* yg = (float*)(ws + YG_OFF);
    float* xfb = (float*)(ws + XFB_OFF);
    float* h1 = (float*)(ws + H1_OFF);
    float* glu = (float*)(ws + GLU_OFF);
    float* h2 = (float*)(ws + H2_OFF);
    float* out = (float*)d_out;

    // 1) xz = x(flip per dir) @ Win^T
    gemm_k<0><<<dim3(128, 8, 2), 256, 0, stream>>>(
        x, nullptr, f_Win, b_Win, nullptr, nullptr, nullptr, nullptr, nullptr,
        xz, 512, 128, 128, 512, 0, (long)NTOK * 512);
    // 2) xi = silu(causal_conv4(xz[:, :256]))
    conv_silu_k<<<dim3(NTOK, 2), 256, 0, stream>>>(xz, f_convw, b_convw,
                                                   f_convb, b_convb, xi);
    // 3) xdbc = xi @ Wx^T (N=520 ragged)
    gemm_k<1><<<dim3(128, 9, 2), 256, 0, stream>>>(
        xi, nullptr, f_Wx, b_Wx, nullptr, nullptr, nullptr, nullptr, nullptr,
        xdbc, 520, 256, 256, 520, (long)NTOK * 256, (long)NTOK * 520);
    // 4) meta = pack(dt, dt*u, u*D, silu(z))
    dt_k<<<dim3(NTOK, 2), 256, 0, stream>>>(xdbc, xi, xz, f_Wdt, b_Wdt,
                                            f_bdt, b_bdt, f_D, b_D, meta);
    // 5) selective scan -> yg
    scan_k<<<512, 256, 0, stream>>>(xdbc, meta, f_Alog, b_Alog, yg);
    // 6) xfb[dir] = x(flip) + (yg @ Wout^T) * scale
    gemm_k<2><<<dim3(128, 2, 2), 256, 0, stream>>>(
        yg, nullptr, f_Wout, b_Wout, nullptr, nullptr, x, fscale, bscale, xfb,
        128, 256, 256, 128, (long)NTOK * 256, (long)NTOK * 128);
    // 7) h1 = concat(xf, xb) @ convf_w^T + convf_b
    gemm_k<3><<<dim3(128, 8, 1), 256, 0, stream>>>(
        xfb, xfb + (long)NTOK * 128, convf_w, convf_w, convf_b, convf_b,
        nullptr, nullptr, nullptr, h1, 512, 256, 128, 512, 0, 0);
    // 8) dwconv3(same) + GLU
    dwglu_k<<<NTOK, 256, 0, stream>>>(h1, dw_w, dw_b, glu);
    // 9) h2 = glu @ convo_w^T + convo_b
    gemm_k<4><<<dim3(128, 2, 1), 256, 0, stream>>>(
        glu, nullptr, convo_w, convo_w, convo_b, convo_b, nullptr, nullptr,
        nullptr, h2, 128, 256, 256, 128, 0, 0);
    // 10) grouped RMS norm -> out
    rmsnorm_k<<<NTOK, 128, 0, stream>>>(h2, gamma, out);
}

// Round 5
// 769.732 us; speedup vs baseline: 2.6994x; 1.0295x over previous
//
#include <hip/hip_runtime.h>
#include <hip/hip_bf16.h>
#include <math.h>

// ---------------- problem constants ----------------
#define S_LEN 2048
#define NB 4
#define NTOK 8192          // NB * S_LEN
#define DM 128             // d_model
#define DI 256             // d_inner
#define DS 256             // d_state
#define XDBC_N 520         // 8 + 256 + 256

// ---------------- workspace layout (bytes), peak < 118 MB (proven ok @126) ----
// A [0, 33.55M):      meta (dead after scan)  -> h1 fp32 (16.8M, gemm3 out)
// B [33.55, 67.63M):  xdbc (dead after scan)  -> glu (8.4M) | h2 (4.2M)
// C [67.63, 101.19M): xz fp32 (dead after dt_k) -> yg (16.8M)
// D [101.19, ...):    bf16 pack area (xi16, xfb16, xbf, weights)
#define META_OFF  0ull
#define XDBC_OFF  33554432ull
#define XZ_OFF    67633152ull
#define YG_OFF    XZ_OFF
#define H1_OFF    META_OFF
#define GLU_OFF   XDBC_OFF
#define H2_OFF    (XDBC_OFF + 8388608ull)
#define XI16_OFF  101187584ull                 // 2*8192*256*2 = 8,388,608
#define XFB16_OFF 109576192ull                 // 2*8192*128*2 = 4,194,304
#define XBF_OFF   113770496ull                 // 8192*128*2   = 2,097,152
#define WIN16_OFF 115867648ull                 // 2*512*128*2  =   262,144
#define WX16_OFF  116129792ull                 // 2*576*256*2  =   589,824 (padded 520->576)
#define CVF16_OFF 116719616ull                 // 512*256*2    =   262,144

struct alignas(8) Meta {
    _Float16 dt, p, pd, gz;  // dt, dt*u, u*D, silu(z)
};

typedef __attribute__((ext_vector_type(8))) short bf16x8;
typedef __attribute__((ext_vector_type(4))) float floatx4;

__device__ __forceinline__ float sigmoidf_(float x) {
    return 1.0f / (1.0f + __expf(-x));
}

// ================= fp32 -> bf16 repack =================
__global__ __launch_bounds__(256) void repack_k(const float* __restrict__ src,
                                                __hip_bfloat16* __restrict__ dst,
                                                int n) {
    int i = blockIdx.x * 256 + threadIdx.x;
    if (i < n) dst[i] = __float2bfloat16(src[i]);
}

// Wx [520][256] -> padded [576][256] bf16 (zero rows 520..575)
__global__ __launch_bounds__(256) void repack_wx_k(const float* __restrict__ src,
                                                   __hip_bfloat16* __restrict__ dst) {
    int i = blockIdx.x * 256 + threadIdx.x;  // over 576*256
    int nrow = i >> 8, k = i & 255;
    float v = (nrow < 520) ? src[nrow * 256 + k] : 0.f;
    dst[i] = __float2bfloat16(v);
}

// ================= bf16 MFMA GEMM (LDS-free; weights L2-resident) =========
// C[m,n] = sum_k A[m,k] * W[n,k], 64x64 tile per block, 4 waves (16 rows each),
// mfma_f32_16x16x32_bf16; a/b frags: [row=lane&15][k=(lane>>4)*8+j].
// MODE 0: A = xbf flip-gather per dir, K=128 -> xz fp32
// MODE 1: A = xi16[dir],               K=256 -> xdbc fp32 (N=520, W padded 576)
// MODE 3: A = xfb16 concat (k<128 -> dir0, else dir1), K=256 -> h1 fp32 +bias
template <int MODE>
__global__ __launch_bounds__(256) void mgemm_k(
    const __hip_bfloat16* __restrict__ A0, const __hip_bfloat16* __restrict__ A1,
    const __hip_bfloat16* __restrict__ W0, const __hip_bfloat16* __restrict__ W1,
    const float* __restrict__ bias, float* __restrict__ C,
    int N, int K, int ldc, long cDirStride) {
    const int dir = blockIdx.z;
    const int m0 = blockIdx.x * 64, n0 = blockIdx.y * 64;
    const int tid = threadIdx.x;
    const int w = tid >> 6, lane = tid & 63;
    const int lm = lane & 15, lq = lane >> 4;
    const __hip_bfloat16* W = dir ? W1 : W0;
    float* Cp = C + (long)dir * cDirStride;

    const int mrow = m0 + 16 * w + lm;  // a-frag source row
    const __hip_bfloat16* Abase = nullptr;
    if constexpr (MODE == 0) {
        int b = mrow >> 11, s = mrow & 2047;
        int s2 = dir ? (2047 - s) : s;
        Abase = A0 + ((long)(b * 2048 + s2)) * 128;
    } else if constexpr (MODE == 1) {
        Abase = A0 + (long)dir * NTOK * 256 + (long)mrow * 256;
    }

    floatx4 acc[4];
#pragma unroll
    for (int c = 0; c < 4; ++c) acc[c] = (floatx4){0.f, 0.f, 0.f, 0.f};

    for (int k0 = 0; k0 < K; k0 += 32) {
        bf16x8 af;
        if constexpr (MODE == 3) {
            const __hip_bfloat16* Ab =
                (k0 < 128 ? A0 : A1) + (long)mrow * 128 + (k0 & 127);
            af = *(const bf16x8*)(Ab + lq * 8);
        } else {
            af = *(const bf16x8*)(Abase + k0 + lq * 8);
        }
#pragma unroll
        for (int c = 0; c < 4; ++c) {
            bf16x8 bfr = *(const bf16x8*)(W + (long)(n0 + 16 * c + lm) * K +
                                          k0 + lq * 8);
            acc[c] = __builtin_amdgcn_mfma_f32_16x16x32_bf16(af, bfr, acc[c],
                                                             0, 0, 0);
        }
    }

    // store: D[row=(lane>>4)*4+r][col=lane&15]
#pragma unroll
    for (int c = 0; c < 4; ++c) {
        int col = n0 + 16 * c + lm;
        if (col < N) {
            float bv = (MODE == 3) ? bias[col] : 0.f;
#pragma unroll
            for (int r = 0; r < 4; ++r) {
                int row = m0 + 16 * w + lq * 4 + r;
                Cp[(long)row * ldc + col] = acc[c][r] + bv;
            }
        }
    }
}

// ================= fp32 tiled GEMM (modes 2,4 only) =================
// MODE 2: A = yg; epi: resid x(flip) + c*scale -> xfb16 (bf16 out!)
// MODE 4: A = glu; +bias                        -> h2 fp32
template <int MODE>
__global__ __launch_bounds__(256) void gemm_k(
    const float* __restrict__ A0,
    const float* __restrict__ W0, const float* __restrict__ W1,
    const float* __restrict__ bias0,
    const float* __restrict__ resid,
    const float* __restrict__ sc0, const float* __restrict__ sc1,
    void* __restrict__ Cv, int N, int K, int lda, int ldc,
    long aDirStride, long cDirStride) {
    const int dir = blockIdx.z;
    const int m0 = blockIdx.x * 64;
    const int n0 = blockIdx.y * 64;
    const float* W = dir ? W1 : W0;
    const float* Adir = A0 + (long)dir * aDirStride;

    __shared__ float As[32][68];
    __shared__ float Ws[32][68];

    const int tid = threadIdx.x;
    const int rr = tid >> 3;
    const int cq = tid & 7;
    const int tm = tid & 15;
    const int tn = tid >> 4;

    float acc[4][4];
#pragma unroll
    for (int i = 0; i < 4; ++i)
#pragma unroll
        for (int j = 0; j < 4; ++j) acc[i][j] = 0.f;

    for (int k0 = 0; k0 < K; k0 += 32) {
#pragma unroll
        for (int h = 0; h < 2; ++h) {
            int m = m0 + rr + h * 32;
            const float* ap = Adir + (long)m * lda + k0;
            float4 v = *(const float4*)(ap + cq * 4);
            As[cq * 4 + 0][rr + h * 32] = v.x;
            As[cq * 4 + 1][rr + h * 32] = v.y;
            As[cq * 4 + 2][rr + h * 32] = v.z;
            As[cq * 4 + 3][rr + h * 32] = v.w;
        }
#pragma unroll
        for (int h = 0; h < 2; ++h) {
            int n = n0 + rr + h * 32;
            float4 v;
            if (n < N)
                v = *(const float4*)(W + (long)n * K + k0 + cq * 4);
            else
                v = make_float4(0.f, 0.f, 0.f, 0.f);
            Ws[cq * 4 + 0][rr + h * 32] = v.x;
            Ws[cq * 4 + 1][rr + h * 32] = v.y;
            Ws[cq * 4 + 2][rr + h * 32] = v.z;
            Ws[cq * 4 + 3][rr + h * 32] = v.w;
        }
        __syncthreads();
#pragma unroll
        for (int kk = 0; kk < 32; ++kk) {
            float4 a = *(const float4*)&As[kk][tm * 4];
            float4 w = *(const float4*)&Ws[kk][tn * 4];
            acc[0][0] = fmaf(a.x, w.x, acc[0][0]);
            acc[0][1] = fmaf(a.x, w.y, acc[0][1]);
            acc[0][2] = fmaf(a.x, w.z, acc[0][2]);
            acc[0][3] = fmaf(a.x, w.w, acc[0][3]);
            acc[1][0] = fmaf(a.y, w.x, acc[1][0]);
            acc[1][1] = fmaf(a.y, w.y, acc[1][1]);
            acc[1][2] = fmaf(a.y, w.z, acc[1][2]);
            acc[1][3] = fmaf(a.y, w.w, acc[1][3]);
            acc[2][0] = fmaf(a.z, w.x, acc[2][0]);
            acc[2][1] = fmaf(a.z, w.y, acc[2][1]);
            acc[2][2] = fmaf(a.z, w.z, acc[2][2]);
            acc[2][3] = fmaf(a.z, w.w, acc[2][3]);
            acc[3][0] = fmaf(a.w, w.x, acc[3][0]);
            acc[3][1] = fmaf(a.w, w.y, acc[3][1]);
            acc[3][2] = fmaf(a.w, w.z, acc[3][2]);
            acc[3][3] = fmaf(a.w, w.w, acc[3][3]);
        }
        __syncthreads();
    }

    const int n = n0 + tn * 4;
#pragma unroll
    for (int i = 0; i < 4; ++i) {
        int m = m0 + tm * 4 + i;
        float4 v = make_float4(acc[i][0], acc[i][1], acc[i][2], acc[i][3]);
        if constexpr (MODE == 2) {
            int b = m >> 11, s = m & 2047;
            int s2 = dir ? (S_LEN - 1 - s) : s;
            const float* xr = resid + ((long)(b * S_LEN + s2)) * DM + n;
            const float* sc = dir ? sc1 : sc0;
            __hip_bfloat16 t[4];
            t[0] = __float2bfloat16(fmaf(v.x, sc[n + 0], xr[0]));
            t[1] = __float2bfloat16(fmaf(v.y, sc[n + 1], xr[1]));
            t[2] = __float2bfloat16(fmaf(v.z, sc[n + 2], xr[2]));
            t[3] = __float2bfloat16(fmaf(v.w, sc[n + 3], xr[3]));
            __hip_bfloat16* Cp = (__hip_bfloat16*)Cv + (long)dir * cDirStride;
            *(ushort4*)(Cp + (long)m * ldc + n) = *(const ushort4*)t;
        } else {
            v.x += bias0[n + 0];
            v.y += bias0[n + 1];
            v.z += bias0[n + 2];
            v.w += bias0[n + 3];
            float* Cp = (float*)Cv + (long)dir * cDirStride;
            if (n < N) *(float4*)(Cp + (long)m * ldc + n) = v;
        }
    }
}

// ================= causal dwconv(K=4)+silu -> bf16 xi =================
__global__ __launch_bounds__(256) void conv_silu_k(
    const float* __restrict__ xz, const float* __restrict__ cw0,
    const float* __restrict__ cw1, const float* __restrict__ cb0,
    const float* __restrict__ cb1, __hip_bfloat16* __restrict__ xi16) {
    const int dir = blockIdx.y;
    const int tok = blockIdx.x;
    const int c = threadIdx.x;
    const int s = tok & 2047;
    const long base = ((long)dir * NTOK + tok) * 512;

    const float* cw = dir ? cw1 : cw0;
    float4 w = *(const float4*)(cw + c * 4);
    float a = (dir ? cb1 : cb0)[c];
    float v0 = (s >= 3) ? xz[base - 3 * 512 + c] : 0.f;
    float v1 = (s >= 2) ? xz[base - 2 * 512 + c] : 0.f;
    float v2 = (s >= 1) ? xz[base - 1 * 512 + c] : 0.f;
    float v3 = xz[base + c];
    a = fmaf(w.x, v0, fmaf(w.y, v1, fmaf(w.z, v2, fmaf(w.w, v3, a))));
    xi16[((long)dir * NTOK + tok) * 256 + c] = __float2bfloat16(a * sigmoidf_(a));
}

// ================= dt_k: softplus matvec + pack Meta =================
__global__ __launch_bounds__(256) void dt_k(
    const float* __restrict__ xdbc, const __hip_bfloat16* __restrict__ xi16,
    const float* __restrict__ xz, const float* __restrict__ Wdt0,
    const float* __restrict__ Wdt1, const float* __restrict__ bdt0,
    const float* __restrict__ bdt1, const float* __restrict__ D0,
    const float* __restrict__ D1, Meta* __restrict__ meta) {
    const int dir = blockIdx.y;
    const int tok = blockIdx.x;
    const int d = threadIdx.x;
    __shared__ float r[8];
    const long row = ((long)dir * NTOK + tok) * XDBC_N;
    if (d < 8) r[d] = xdbc[row + d];
    __syncthreads();
    const float* Wd = (dir ? Wdt1 : Wdt0) + d * 8;
    float a = (dir ? bdt1 : bdt0)[d];
#pragma unroll
    for (int k = 0; k < 8; ++k) a = fmaf(r[k], Wd[k], a);
    float dt = (a > 15.f) ? a : log1pf(__expf(a));

    float u = __bfloat162float(xi16[((long)dir * NTOK + tok) * 256 + d]);
    float z = xz[((long)dir * NTOK + tok) * 512 + 256 + d];
    float gz = z * sigmoidf_(z);
    float Dv = (dir ? D1 : D0)[d];

    const int b = tok >> 11, s = tok & 2047;
    Meta m;
    m.dt = (_Float16)dt;
    m.p = (_Float16)(dt * u);
    m.pd = (_Float16)(u * Dv);
    m.gz = (_Float16)gz;
    meta[(((long)dir * 4 + b) * 256 + d) * 2048 + s] = m;
}

// ================= selective scan (unchanged from round 4) =================
__global__ __launch_bounds__(256) void scan_k(
    const float* __restrict__ xdbc, const Meta* __restrict__ meta,
    const float* __restrict__ Alog0, const float* __restrict__ Alog1,
    float* __restrict__ yg) {
    const int wave = threadIdx.x >> 6;
    const int lane = threadIdx.x & 63;
    const int bd = blockIdx.x >> 6;
    const int dg = blockIdx.x & 63;
    const int dir = bd >> 2, b = bd & 3;
    const int d = dg * 4 + wave;

    const float* Alog = dir ? Alog1 : Alog0;
    const float LOG2E = 1.4426950408889634f;
    float4 A2;
    {
        const float* ap = Alog + (long)d * DS + 4 * lane;
        A2.x = -__expf(ap[0]) * LOG2E;
        A2.y = -__expf(ap[1]) * LOG2E;
        A2.z = -__expf(ap[2]) * LOG2E;
        A2.w = -__expf(ap[3]) * LOG2E;
    }
    float4 h = make_float4(0.f, 0.f, 0.f, 0.f);

    const long tokBase = (long)dir * NTOK + (long)b * S_LEN;
    const float* xrow = xdbc + tokBase * XDBC_N;
    const Meta* mp = meta + (((long)dir * 4 + b) * 256 + d) * 2048;
    float* yp = yg + tokBase * 256 + d;

    float4 Bs[8], Cs[8];
    Meta Ms[8];
#define LD_SLOT(q, t)                                                       \
    {                                                                       \
        const float* r_ = xrow + (long)(t) * XDBC_N;                        \
        Bs[q] = *(const float4*)(r_ + 8 + 4 * lane);                        \
        Cs[q] = *(const float4*)(r_ + 264 + 4 * lane);                      \
        Ms[q] = mp[t];                                                      \
    }
#pragma unroll
    for (int q = 0; q < 8; ++q) LD_SLOT(q, q)

    for (int t = 0; t < S_LEN; t += 8) {
        float acc[8], pd[8], gz2[8];
#pragma unroll
        for (int q = 0; q < 8; ++q) {
            float4 Bv = Bs[q], Cv = Cs[q];
            float dtv = (float)Ms[q].dt;
            float pv = (float)Ms[q].p;
            pd[q] = (float)Ms[q].pd;
            gz2[q] = (float)Ms[q].gz;
            LD_SLOT(q, t + q + 8)  // overrun past S_LEN lands in-ws, unused

            h.x = fmaf(h.x, __builtin_amdgcn_exp2f(dtv * A2.x), pv * Bv.x);
            h.y = fmaf(h.y, __builtin_amdgcn_exp2f(dtv * A2.y), pv * Bv.y);
            h.z = fmaf(h.z, __builtin_amdgcn_exp2f(dtv * A2.z), pv * Bv.z);
            h.w = fmaf(h.w, __builtin_amdgcn_exp2f(dtv * A2.w), pv * Bv.w);

            float a0 = h.x * Cv.x;
            a0 = fmaf(h.y, Cv.y, a0);
            a0 = fmaf(h.z, Cv.z, a0);
            acc[q] = fmaf(h.w, Cv.w, a0);
        }
#pragma unroll
        for (int st = 1; st <= 32; st <<= 1) {
#pragma unroll
            for (int q = 0; q < 8; ++q) acc[q] += __shfl_xor(acc[q], st);
        }
        if (lane == 0) {
#pragma unroll
            for (int q = 0; q < 8; ++q)
                yp[(long)(t + q) * 256] = (pd[q] + acc[q]) * gz2[q];
        }
    }
#undef LD_SLOT
}

// ================= dwconv_same(K=3) + GLU =================
__global__ __launch_bounds__(256) void dwglu_k(
    const float* __restrict__ h1, const float* __restrict__ dww,
    const float* __restrict__ dwb, float* __restrict__ glu) {
    const int tok = blockIdx.x;
    const int c = threadIdx.x;
    const int s = tok & 2047;
    const long row = (long)tok * 512;
    const int c2 = c + 256;

    float xm_a = (s >= 1) ? h1[row - 512 + c] : 0.f;
    float x0_a = h1[row + c];
    float xp_a = (s <= 2046) ? h1[row + 512 + c] : 0.f;
    float xm_b = (s >= 1) ? h1[row - 512 + c2] : 0.f;
    float x0_b = h1[row + c2];
    float xp_b = (s <= 2046) ? h1[row + 512 + c2] : 0.f;

    float a1 = dwb[c];
    a1 = fmaf(dww[c * 3 + 0], xm_a, a1);
    a1 = fmaf(dww[c * 3 + 1], x0_a, a1);
    a1 = fmaf(dww[c * 3 + 2], xp_a, a1);
    float a2 = dwb[c2];
    a2 = fmaf(dww[c2 * 3 + 0], xm_b, a2);
    a2 = fmaf(dww[c2 * 3 + 1], x0_b, a2);
    a2 = fmaf(dww[c2 * 3 + 2], xp_b, a2);

    glu[(long)tok * 256 + c] = a1 * sigmoidf_(a1) * a2;
}

// ================= grouped rms norm (4 groups of 32) =================
__global__ __launch_bounds__(128) void rmsnorm_k(
    const float* __restrict__ h2, const float* __restrict__ gamma,
    float* __restrict__ out) {
    const int tok = blockIdx.x;
    const int c = threadIdx.x;
    float v = h2[(long)tok * 128 + c];
    float ss = v * v;
    ss += __shfl_xor(ss, 1);
    ss += __shfl_xor(ss, 2);
    ss += __shfl_xor(ss, 4);
    ss += __shfl_xor(ss, 8);
    ss += __shfl_xor(ss, 16);
    float r = sqrtf(ss * (1.0f / 32.0f));
    out[(long)tok * 128 + c] = v / (r + 1e-5f) * gamma[c];
}

// ================= host launcher =================
extern "C" void kernel_launch(void* const* d_in, const int* in_sizes, int n_in,
                              void* d_out, int out_size, void* d_ws,
                              size_t ws_size, hipStream_t stream) {
    const float* x = (const float*)d_in[0];
    const float* f_Win = (const float*)d_in[1];
    const float* f_convw = (const float*)d_in[2];
    const float* f_convb = (const float*)d_in[3];
    const float* f_Wx = (const float*)d_in[4];
    const float* f_Wdt = (const float*)d_in[5];
    const float* f_bdt = (const float*)d_in[6];
    const float* f_Alog = (const float*)d_in[7];
    const float* f_D = (const float*)d_in[8];
    const float* f_Wout = (const float*)d_in[9];
    const float* b_Win = (const float*)d_in[10];
    const float* b_convw = (const float*)d_in[11];
    const float* b_convb = (const float*)d_in[12];
    const float* b_Wx = (const float*)d_in[13];
    const float* b_Wdt = (const float*)d_in[14];
    const float* b_bdt = (const float*)d_in[15];
    const float* b_Alog = (const float*)d_in[16];
    const float* b_D = (const float*)d_in[17];
    const float* b_Wout = (const float*)d_in[18];
    const float* fscale = (const float*)d_in[19];
    const float* bscale = (const float*)d_in[20];
    const float* convf_w = (const float*)d_in[21];
    const float* convf_b = (const float*)d_in[22];
    const float* dw_w = (const float*)d_in[23];
    const float* dw_b = (const float*)d_in[24];
    const float* convo_w = (const float*)d_in[25];
    const float* convo_b = (const float*)d_in[26];
    const float* gamma = (const float*)d_in[27];

    char* ws = (char*)d_ws;
    Meta* meta = (Meta*)(ws + META_OFF);
    float* xdbc = (float*)(ws + XDBC_OFF);
    float* xz = (float*)(ws + XZ_OFF);
    float* yg = (float*)(ws + YG_OFF);
    float* h1 = (float*)(ws + H1_OFF);
    float* glu = (float*)(ws + GLU_OFF);
    float* h2 = (float*)(ws + H2_OFF);
    __hip_bfloat16* xi16 = (__hip_bfloat16*)(ws + XI16_OFF);
    __hip_bfloat16* xfb16 = (__hip_bfloat16*)(ws + XFB16_OFF);
    __hip_bfloat16* xbf = (__hip_bfloat16*)(ws + XBF_OFF);
    __hip_bfloat16* Win16 = (__hip_bfloat16*)(ws + WIN16_OFF);   // [2][512*128]
    __hip_bfloat16* Wx16 = (__hip_bfloat16*)(ws + WX16_OFF);     // [2][576*256]
    __hip_bfloat16* cvf16 = (__hip_bfloat16*)(ws + CVF16_OFF);   // [512*256]
    float* out = (float*)d_out;

    // 0) repack activations-input + weights to bf16
    repack_k<<<4096, 256, 0, stream>>>(x, xbf, NTOK * DM);
    repack_k<<<256, 256, 0, stream>>>(f_Win, Win16, 512 * 128);
    repack_k<<<256, 256, 0, stream>>>(b_Win, Win16 + 512 * 128, 512 * 128);
    repack_wx_k<<<576, 256, 0, stream>>>(f_Wx, Wx16);
    repack_wx_k<<<576, 256, 0, stream>>>(b_Wx, Wx16 + 576 * 256);
    repack_k<<<512, 256, 0, stream>>>(convf_w, cvf16, 512 * 256);

    // 1) xz = x(flip per dir) @ Win^T   [MFMA bf16]
    mgemm_k<0><<<dim3(128, 8, 2), 256, 0, stream>>>(
        xbf, nullptr, Win16, Win16 + 512 * 128, nullptr, xz, 512, 128, 512,
        (long)NTOK * 512);
    // 2) xi16 = bf16(silu(causal_conv4(xz[:, :256])))
    conv_silu_k<<<dim3(NTOK, 2), 256, 0, stream>>>(xz, f_convw, b_convw,
                                                   f_convb, b_convb, xi16);
    // 3) xdbc = xi @ Wx^T  [MFMA bf16, N=520 padded to 576]
    mgemm_k<1><<<dim3(128, 9, 2), 256, 0, stream>>>(
        xi16, nullptr, Wx16, Wx16 + 576 * 256, nullptr, xdbc, 520, 256, 520,
        (long)NTOK * 520);
    // 4) meta = pack(dt, dt*u, u*D, silu(z))
    dt_k<<<dim3(NTOK, 2), 256, 0, stream>>>(xdbc, xi16, xz, f_Wdt, b_Wdt,
                                            f_bdt, b_bdt, f_D, b_D, meta);
    // 5) selective scan -> yg (overwrites dead xz region)
    scan_k<<<512, 256, 0, stream>>>(xdbc, meta, f_Alog, b_Alog, yg);
    // 6) xfb16 = bf16(x(flip) + (yg @ Wout^T) * scale)   [fp32 compute]
    gemm_k<2><<<dim3(128, 2, 2), 256, 0, stream>>>(
        yg, f_Wout, b_Wout, nullptr, x, fscale, bscale, xfb16, 128, 256, 256,
        128, (long)NTOK * 256, (long)NTOK * 128);
    // 7) h1 = concat(xf, xb) @ convf_w^T + convf_b   [MFMA bf16]
    mgemm_k<3><<<dim3(128, 8, 1), 256, 0, stream>>>(
        xfb16, xfb16 + (long)NTOK * 128, cvf16, cvf16, convf_b, h1, 512, 256,
        512, 0);
    // 8) dwconv3(same) + GLU
    dwglu_k<<<NTOK, 256, 0, stream>>>(h1, dw_w, dw_b, glu);
    // 9) h2 = glu @ convo_w^T + convo_b   [fp32]
    gemm_k<4><<<dim3(128, 2, 1), 256, 0, stream>>>(
        glu, convo_w, convo_w, convo_b, nullptr, nullptr, nullptr, h2, 128,
        256, 256, 128, 0, 0);
    // 10) grouped RMS norm -> out
    rmsnorm_k<<<NTOK, 128, 0, stream>>>(h2, gamma, out);
}